// Round 2
// baseline (700.598 us; speedup 1.0000x reference)
//
#include <hip/hip_runtime.h>
#include <hip/hip_bf16.h>
#include <math.h>

// ---------------- CSR build ----------------

__global__ void count_kernel(const int* __restrict__ ei, int E, int n, int* __restrict__ deg) {
    int e = blockIdx.x * blockDim.x + threadIdx.x;
    int Etot = E + n;
    if (e >= Etot) return;
    int dst = (e < E) ? ei[E + e] : (e - E);
    atomicAdd(&deg[dst], 1);
}

__global__ void scan_kernel(const int* __restrict__ deg, int* __restrict__ rowptr,
                            int* __restrict__ cursor, int n) {
    __shared__ int wsum[16];
    int t = threadIdx.x;
    int lane = t & 63, wid = t >> 6;
    int carry = 0;
    for (int base = 0; base < n; base += 1024) {
        int i = base + t;
        int v = (i < n) ? deg[i] : 0;
        int val = v;
        #pragma unroll
        for (int off = 1; off < 64; off <<= 1) {
            int nv = __shfl_up(val, off);
            if (lane >= off) val += nv;
        }
        if (lane == 63) wsum[wid] = val;
        __syncthreads();
        int wpre = 0, tot = 0;
        #pragma unroll
        for (int w = 0; w < 16; ++w) {
            int s = wsum[w];
            if (w < wid) wpre += s;
            tot += s;
        }
        int excl = carry + wpre + val - v;
        if (i < n) { rowptr[i] = excl; cursor[i] = excl; }
        carry += tot;
        __syncthreads();
    }
    if (t == 0) rowptr[n] = carry;
}

__global__ void scatter_kernel(const int* __restrict__ ei, int E, int n,
                               int* __restrict__ cursor, int* __restrict__ ssrc) {
    int e = blockIdx.x * blockDim.x + threadIdx.x;
    int Etot = E + n;
    if (e >= Etot) return;
    int src, dst;
    if (e < E) { src = ei[e]; dst = ei[E + e]; }
    else       { src = e - E; dst = e - E; }
    int pos = atomicAdd(&cursor[dst], 1);
    ssrc[pos] = src;
}

// ---------------- fp32 NT GEMM: C[M,N] = A[M,K] * B[N,K]^T ----------------

template<int BK>
__global__ void gemm_nt_kernel(const float* __restrict__ A, const float* __restrict__ B,
                               float* __restrict__ C, int M, int N, int K) {
    constexpr int BM = 64, BN = 64;
    __shared__ float As[BK][BM + 4];
    __shared__ float Bs[BK][BN + 4];
    const int bm = blockIdx.y * BM;
    const int bn = blockIdx.x * BN;
    const int t = threadIdx.x;
    const int tx = t & 15, ty = t >> 4;
    const int r = t >> 2, kc = (t & 3) << 2;
    float acc[4][4] = {};
    for (int k0 = 0; k0 < K; k0 += BK) {
        float4 av = {0.f, 0.f, 0.f, 0.f}, bv = {0.f, 0.f, 0.f, 0.f};
        if (bm + r < M) av = *(const float4*)(A + (size_t)(bm + r) * K + k0 + kc);
        if (bn + r < N) bv = *(const float4*)(B + (size_t)(bn + r) * K + k0 + kc);
        As[kc + 0][r] = av.x; As[kc + 1][r] = av.y; As[kc + 2][r] = av.z; As[kc + 3][r] = av.w;
        Bs[kc + 0][r] = bv.x; Bs[kc + 1][r] = bv.y; Bs[kc + 2][r] = bv.z; Bs[kc + 3][r] = bv.w;
        __syncthreads();
        #pragma unroll
        for (int k = 0; k < BK; ++k) {
            float4 a = *(const float4*)&As[k][ty << 2];
            float4 b = *(const float4*)&Bs[k][tx << 2];
            float af[4] = {a.x, a.y, a.z, a.w};
            float bf[4] = {b.x, b.y, b.z, b.w};
            #pragma unroll
            for (int i = 0; i < 4; ++i)
                #pragma unroll
                for (int j = 0; j < 4; ++j)
                    acc[i][j] += af[i] * bf[j];
        }
        __syncthreads();
    }
    #pragma unroll
    for (int i = 0; i < 4; ++i) {
        int row = bm + (ty << 2) + i;
        if (row < M) {
            float4 o = make_float4(acc[i][0], acc[i][1], acc[i][2], acc[i][3]);
            *(float4*)(C + (size_t)row * N + bn + (tx << 2)) = o;
        }
    }
}

// ---------------- attention logits: al[n,h] = sum_c h[n,h,c]*a[h,c] ----------------

__global__ void al_kernel(const float* __restrict__ hmat, int n, int HC,
                          const float* __restrict__ a_src, const float* __restrict__ a_dst,
                          float* __restrict__ al_s, float* __restrict__ al_d) {
    int node = blockIdx.x * 4 + (threadIdx.x >> 6);
    if (node >= n) return;
    int l = threadIdx.x & 63;
    int q = HC >> 6;                       // elems per lane (4 or 5)
    const float* hp = hmat + (size_t)node * HC + q * l;
    float ps = 0.f, pd = 0.f;
    for (int j = 0; j < q; ++j) {
        float hv = hp[j];
        ps += hv * a_src[q * l + j];
        pd += hv * a_dst[q * l + j];
    }
    #pragma unroll
    for (int mask = 1; mask <= 4; mask <<= 1) {
        ps += __shfl_xor(ps, mask);
        pd += __shfl_xor(pd, mask);
    }
    if ((l & 7) == 0) {
        al_s[node * 8 + (l >> 3)] = ps;
        al_d[node * 8 + (l >> 3)] = pd;
    }
}

// ---------------- layer-1 aggregation: softmax-weighted sum + bias + ELU ----------------

__device__ __forceinline__ float lrelu(float e) { return (e > 0.f) ? e : 0.2f * e; }

__global__ void agg1_kernel(const float* __restrict__ h1, const float* __restrict__ als,
                            const float* __restrict__ aldv, const float* __restrict__ b1,
                            const int* __restrict__ rowptr, const int* __restrict__ ssrc,
                            float* __restrict__ hout, int n) {
    int node = blockIdx.x * 4 + (threadIdx.x >> 6);
    if (node >= n) return;
    int l = threadIdx.x & 63;
    int h = l >> 3;
    float ald = aldv[node * 8 + h];
    int beg = rowptr[node], end = rowptr[node + 1];
    float m = -1e30f;
    for (int p = beg; p < end; ++p) {
        int s = ssrc[p];
        m = fmaxf(m, lrelu(als[s * 8 + h] + ald));
    }
    float den = 0.f, a0 = 0.f, a1 = 0.f, a2 = 0.f, a3 = 0.f;
    for (int p = beg; p < end; ++p) {
        int s = ssrc[p];
        float ee = __expf(lrelu(als[s * 8 + h] + ald) - m);
        den += ee;
        float4 hv = *(const float4*)(h1 + (size_t)s * 256 + l * 4);
        a0 += ee * hv.x; a1 += ee * hv.y; a2 += ee * hv.z; a3 += ee * hv.w;
    }
    float inv = 1.f / den;
    float4 bv = *(const float4*)(b1 + l * 4);
    float v0 = a0 * inv + bv.x, v1 = a1 * inv + bv.y;
    float v2 = a2 * inv + bv.z, v3 = a3 * inv + bv.w;
    float4 o;
    o.x = (v0 > 0.f) ? v0 : __expf(v0) - 1.f;
    o.y = (v1 > 0.f) ? v1 : __expf(v1) - 1.f;
    o.z = (v2 > 0.f) ? v2 : __expf(v2) - 1.f;
    o.w = (v3 > 0.f) ? v3 : __expf(v3) - 1.f;
    *(float4*)(hout + (size_t)node * 256 + l * 4) = o;
}

// ---------------- layer-2 aggregation + head-mean + bias + log_softmax ----------------

__global__ void agg2_kernel(const float* __restrict__ h2, const float* __restrict__ als,
                            const float* __restrict__ aldv, const float* __restrict__ b2,
                            const int* __restrict__ rowptr, const int* __restrict__ ssrc,
                            float* __restrict__ out, int n) {
    int node = blockIdx.x * 4 + (threadIdx.x >> 6);
    if (node >= n) return;
    int l = threadIdx.x & 63;
    int h = l >> 3;
    float ald = aldv[node * 8 + h];
    int beg = rowptr[node], end = rowptr[node + 1];
    float m = -1e30f;
    for (int p = beg; p < end; ++p) {
        int s = ssrc[p];
        m = fmaxf(m, lrelu(als[s * 8 + h] + ald));
    }
    float den = 0.f, a0 = 0.f, a1 = 0.f, a2 = 0.f, a3 = 0.f, a4 = 0.f;
    for (int p = beg; p < end; ++p) {
        int s = ssrc[p];
        float ee = __expf(lrelu(als[s * 8 + h] + ald) - m);
        den += ee;
        const float* hp = h2 + (size_t)s * 320 + 5 * l;   // 40*h + 5*(l&7) == 5*l
        a0 += ee * hp[0]; a1 += ee * hp[1]; a2 += ee * hp[2];
        a3 += ee * hp[3]; a4 += ee * hp[4];
    }
    float inv = 1.f / den;
    float v[5] = {a0 * inv, a1 * inv, a2 * inv, a3 * inv, a4 * inv};
    // mean over 8 heads: lanes sharing (l&7) differ in bits 3..5
    #pragma unroll
    for (int j = 0; j < 5; ++j) {
        float s = v[j];
        s += __shfl_xor(s, 8);
        s += __shfl_xor(s, 16);
        s += __shfl_xor(s, 32);
        v[j] = 0.125f * s + b2[5 * (l & 7) + j];
    }
    // log_softmax over 40 classes spread across lanes (l&7)*5..+4
    float mx = v[0];
    #pragma unroll
    for (int j = 1; j < 5; ++j) mx = fmaxf(mx, v[j]);
    #pragma unroll
    for (int mask = 1; mask <= 4; mask <<= 1) mx = fmaxf(mx, __shfl_xor(mx, mask));
    float se = 0.f;
    #pragma unroll
    for (int j = 0; j < 5; ++j) se += __expf(v[j] - mx);
    #pragma unroll
    for (int mask = 1; mask <= 4; mask <<= 1) se += __shfl_xor(se, mask);
    float lse = mx + __logf(se);
    if (h == 0) {
        int o = node * 40 + 5 * (l & 7);
        #pragma unroll
        for (int j = 0; j < 5; ++j) out[o + j] = v[j] - lse;
    }
}

// ---------------- launch ----------------

extern "C" void kernel_launch(void* const* d_in, const int* in_sizes, int n_in,
                              void* d_out, int out_size, void* d_ws, size_t ws_size,
                              hipStream_t stream) {
    const float* x      = (const float*)d_in[0];
    const int*   ei     = (const int*)d_in[1];
    const float* W1     = (const float*)d_in[2];
    const float* a_src1 = (const float*)d_in[3];
    const float* a_dst1 = (const float*)d_in[4];
    const float* b1     = (const float*)d_in[5];
    const float* W2     = (const float*)d_in[6];
    const float* a_src2 = (const float*)d_in[7];
    const float* a_dst2 = (const float*)d_in[8];
    const float* b2     = (const float*)d_in[9];
    float* out = (float*)d_out;

    const int n    = in_sizes[0] / 128;   // 50000
    const int E    = in_sizes[1] / 2;     // 800000
    const int Etot = E + n;

    char* w = (char*)d_ws;
    auto take = [&](size_t bytes) {
        char* p = w;
        w += (bytes + 255) & ~(size_t)255;
        return p;
    };
    int*   deg    = (int*)take((size_t)n * 4);
    int*   rowptr = (int*)take((size_t)(n + 1) * 4);
    int*   cursor = (int*)take((size_t)n * 4);
    int*   ssrc   = (int*)take((size_t)Etot * 4);
    float* h1     = (float*)take((size_t)n * 320 * 4);   // h1 uses 256/row; reused as h2 (320/row)
    float* helu   = (float*)take((size_t)n * 256 * 4);
    float* als1   = (float*)take((size_t)n * 8 * 4);
    float* ald1   = (float*)take((size_t)n * 8 * 4);
    float* als2   = (float*)take((size_t)n * 8 * 4);
    float* ald2   = (float*)take((size_t)n * 8 * 4);
    float* h2     = h1;   // h1 dead once helu is produced

    hipMemsetAsync(deg, 0, (size_t)n * 4, stream);

    int eb = (Etot + 255) / 256;
    count_kernel<<<eb, 256, 0, stream>>>(ei, E, n, deg);
    scan_kernel<<<1, 1024, 0, stream>>>(deg, rowptr, cursor, n);
    scatter_kernel<<<eb, 256, 0, stream>>>(ei, E, n, cursor, ssrc);

    // layer 1
    gemm_nt_kernel<16><<<dim3(256 / 64, (n + 63) / 64), 256, 0, stream>>>(x, W1, h1, n, 256, 128);
    int nb4 = (n + 3) / 4;
    al_kernel<<<nb4, 256, 0, stream>>>(h1, n, 256, a_src1, a_dst1, als1, ald1);
    agg1_kernel<<<nb4, 256, 0, stream>>>(h1, als1, ald1, b1, rowptr, ssrc, helu, n);

    // layer 2
    gemm_nt_kernel<16><<<dim3(320 / 64, (n + 63) / 64), 256, 0, stream>>>(helu, W2, h2, n, 320, 256);
    al_kernel<<<nb4, 256, 0, stream>>>(h2, n, 320, a_src2, a_dst2, als2, ald2);
    agg2_kernel<<<nb4, 256, 0, stream>>>(h2, als2, ald2, b2, rowptr, ssrc, out, n);
}

// Round 3
// 630.618 us; speedup vs baseline: 1.1110x; 1.1110x over previous
//
#include <hip/hip_runtime.h>
#include <hip/hip_bf16.h>
#include <math.h>

typedef unsigned short ushort_t;
typedef __attribute__((ext_vector_type(8))) short short8;
typedef __attribute__((ext_vector_type(4))) float f32x4;
typedef __attribute__((ext_vector_type(4))) unsigned short u16x4;

static __device__ __forceinline__ float b2f(ushort_t u) {
    union { unsigned int i; float f; } v; v.i = ((unsigned int)u) << 16; return v.f;
}
static __device__ __forceinline__ ushort_t f2b(float f) {
    unsigned int x = __float_as_uint(f);
    unsigned int r = (x + 0x7fffu + ((x >> 16) & 1u)) >> 16;
    return (ushort_t)r;
}

// ---------------- fp32 -> bf16 convert ----------------

__global__ void conv_kernel(const float* __restrict__ src, ushort_t* __restrict__ dst, int n4) {
    for (int i = blockIdx.x * blockDim.x + threadIdx.x; i < n4; i += gridDim.x * blockDim.x) {
        float4 v = *(const float4*)(src + i * 4);
        u16x4 o = { f2b(v.x), f2b(v.y), f2b(v.z), f2b(v.w) };
        *(u16x4*)(dst + i * 4) = o;
    }
}

// ---------------- CSR build ----------------

__global__ void count_kernel(const int* __restrict__ ei, int E, int n, int* __restrict__ deg) {
    int e = blockIdx.x * blockDim.x + threadIdx.x;
    int Etot = E + n;
    if (e >= Etot) return;
    int dst = (e < E) ? ei[E + e] : (e - E);
    atomicAdd(&deg[dst], 1);
}

__global__ void scan_kernel(const int* __restrict__ deg, int* __restrict__ rowptr,
                            int* __restrict__ cursor, int n) {
    __shared__ int wsum[16];
    int t = threadIdx.x;
    int lane = t & 63, wid = t >> 6;
    int carry = 0;
    for (int base = 0; base < n; base += 1024) {
        int i = base + t;
        int v = (i < n) ? deg[i] : 0;
        int val = v;
        #pragma unroll
        for (int off = 1; off < 64; off <<= 1) {
            int nv = __shfl_up(val, off);
            if (lane >= off) val += nv;
        }
        if (lane == 63) wsum[wid] = val;
        __syncthreads();
        int wpre = 0, tot = 0;
        #pragma unroll
        for (int w = 0; w < 16; ++w) {
            int s = wsum[w];
            if (w < wid) wpre += s;
            tot += s;
        }
        int excl = carry + wpre + val - v;
        if (i < n) { rowptr[i] = excl; cursor[i] = excl; }
        carry += tot;
        __syncthreads();
    }
    if (t == 0) rowptr[n] = carry;
}

__global__ void scatter_kernel(const int* __restrict__ ei, int E, int n,
                               int* __restrict__ cursor, int* __restrict__ ssrc) {
    int e = blockIdx.x * blockDim.x + threadIdx.x;
    int Etot = E + n;
    if (e >= Etot) return;
    int src, dst;
    if (e < E) { src = ei[e]; dst = ei[E + e]; }
    else       { src = e - E; dst = e - E; }
    int pos = atomicAdd(&cursor[dst], 1);
    ssrc[pos] = src;
}

// ---------------- bf16 MFMA NT GEMM: C[M,N] = A[M,K] * B[N,K]^T ----------------
// one block = 4 waves = 64 rows; each wave owns 16 rows x full N.
// frag A: row=l&15, k=(l>>4)*8+j (contiguous 8 bf16). frag B: col=l&15, same k.
// C/D: col=lane&15, row=(lane>>4)*4+j  [verified m89/m91]

template<int NFRAG, int K>
__global__ __launch_bounds__(256) void gemm_nt_bf16(const ushort_t* __restrict__ A,
                                                    const ushort_t* __restrict__ B,
                                                    ushort_t* __restrict__ C, int M) {
    const int w = threadIdx.x >> 6, l = threadIdx.x & 63;
    const int r0 = blockIdx.x * 64 + w * 16;
    int arow = r0 + (l & 15);
    if (arow >= M) arow = M - 1;
    const int koff = (l >> 4) * 8;
    const int N = NFRAG * 16;
    f32x4 acc[NFRAG];
    #pragma unroll
    for (int i = 0; i < NFRAG; ++i) acc[i] = (f32x4){0.f, 0.f, 0.f, 0.f};
    const ushort_t* ap = A + (size_t)arow * K + koff;
    const ushort_t* bp = B + (size_t)(l & 15) * K + koff;
    #pragma unroll 1
    for (int k0 = 0; k0 < K; k0 += 32) {
        short8 a = *(const short8*)(ap + k0);
        #pragma unroll
        for (int nf = 0; nf < NFRAG; ++nf) {
            short8 b = *(const short8*)(bp + (size_t)nf * 16 * K + k0);
            acc[nf] = __builtin_amdgcn_mfma_f32_16x16x32_bf16(a, b, acc[nf], 0, 0, 0);
        }
    }
    const int crow0 = r0 + (l >> 4) * 4;
    #pragma unroll
    for (int nf = 0; nf < NFRAG; ++nf) {
        #pragma unroll
        for (int j = 0; j < 4; ++j) {
            int row = crow0 + j;
            if (row < M) C[(size_t)row * N + nf * 16 + (l & 15)] = f2b(acc[nf][j]);
        }
    }
}

// ---------------- attention logits from bf16 h ----------------

__global__ void al_kernel(const ushort_t* __restrict__ hmat, int n, int HC,
                          const float* __restrict__ a_src, const float* __restrict__ a_dst,
                          float* __restrict__ al_s, float* __restrict__ al_d) {
    int node = blockIdx.x * 4 + (threadIdx.x >> 6);
    if (node >= n) return;
    int l = threadIdx.x & 63;
    int q = HC >> 6;                       // elems per lane (4 or 5)
    const ushort_t* hp = hmat + (size_t)node * HC + q * l;
    float ps = 0.f, pd = 0.f;
    for (int j = 0; j < q; ++j) {
        float hv = b2f(hp[j]);
        ps += hv * a_src[q * l + j];
        pd += hv * a_dst[q * l + j];
    }
    #pragma unroll
    for (int mask = 1; mask <= 4; mask <<= 1) {
        ps += __shfl_xor(ps, mask);
        pd += __shfl_xor(pd, mask);
    }
    if ((l & 7) == 0) {
        al_s[node * 8 + (l >> 3)] = ps;
        al_d[node * 8 + (l >> 3)] = pd;
    }
}

// ---------------- layer-1 aggregation (bf16 gather) + bias + ELU -> bf16 ----------------

__device__ __forceinline__ float lrelu(float e) { return (e > 0.f) ? e : 0.2f * e; }

__global__ void agg1_kernel(const ushort_t* __restrict__ h1, const float* __restrict__ als,
                            const float* __restrict__ aldv, const float* __restrict__ b1,
                            const int* __restrict__ rowptr, const int* __restrict__ ssrc,
                            ushort_t* __restrict__ hout, int n) {
    int node = blockIdx.x * 4 + (threadIdx.x >> 6);
    if (node >= n) return;
    int l = threadIdx.x & 63;
    int h = l >> 3;
    float ald = aldv[node * 8 + h];
    int beg = rowptr[node], end = rowptr[node + 1];
    float m = -1e30f;
    for (int p = beg; p < end; ++p) {
        int s = ssrc[p];
        m = fmaxf(m, lrelu(als[s * 8 + h] + ald));
    }
    float den = 0.f, a0 = 0.f, a1 = 0.f, a2 = 0.f, a3 = 0.f;
    for (int p = beg; p < end; ++p) {
        int s = ssrc[p];
        float ee = __expf(lrelu(als[s * 8 + h] + ald) - m);
        den += ee;
        u16x4 hv = *(const u16x4*)(h1 + (size_t)s * 256 + l * 4);
        a0 += ee * b2f(hv.x); a1 += ee * b2f(hv.y);
        a2 += ee * b2f(hv.z); a3 += ee * b2f(hv.w);
    }
    float inv = 1.f / den;
    float4 bv = *(const float4*)(b1 + l * 4);
    float v0 = a0 * inv + bv.x, v1 = a1 * inv + bv.y;
    float v2 = a2 * inv + bv.z, v3 = a3 * inv + bv.w;
    u16x4 o;
    o.x = f2b((v0 > 0.f) ? v0 : __expf(v0) - 1.f);
    o.y = f2b((v1 > 0.f) ? v1 : __expf(v1) - 1.f);
    o.z = f2b((v2 > 0.f) ? v2 : __expf(v2) - 1.f);
    o.w = f2b((v3 > 0.f) ? v3 : __expf(v3) - 1.f);
    *(u16x4*)(hout + (size_t)node * 256 + l * 4) = o;
}

// ---------------- layer-2 aggregation + head-mean + bias + log_softmax ----------------

__global__ void agg2_kernel(const ushort_t* __restrict__ h2, const float* __restrict__ als,
                            const float* __restrict__ aldv, const float* __restrict__ b2,
                            const int* __restrict__ rowptr, const int* __restrict__ ssrc,
                            float* __restrict__ out, int n) {
    int node = blockIdx.x * 4 + (threadIdx.x >> 6);
    if (node >= n) return;
    int l = threadIdx.x & 63;
    int h = l >> 3;
    float ald = aldv[node * 8 + h];
    int beg = rowptr[node], end = rowptr[node + 1];
    float m = -1e30f;
    for (int p = beg; p < end; ++p) {
        int s = ssrc[p];
        m = fmaxf(m, lrelu(als[s * 8 + h] + ald));
    }
    float den = 0.f, a0 = 0.f, a1 = 0.f, a2 = 0.f, a3 = 0.f, a4 = 0.f;
    for (int p = beg; p < end; ++p) {
        int s = ssrc[p];
        float ee = __expf(lrelu(als[s * 8 + h] + ald) - m);
        den += ee;
        const ushort_t* hp = h2 + (size_t)s * 320 + 5 * l;   // 40*h + 5*(l&7) == 5*l
        a0 += ee * b2f(hp[0]); a1 += ee * b2f(hp[1]); a2 += ee * b2f(hp[2]);
        a3 += ee * b2f(hp[3]); a4 += ee * b2f(hp[4]);
    }
    float inv = 1.f / den;
    float v[5] = {a0 * inv, a1 * inv, a2 * inv, a3 * inv, a4 * inv};
    #pragma unroll
    for (int j = 0; j < 5; ++j) {
        float s = v[j];
        s += __shfl_xor(s, 8);
        s += __shfl_xor(s, 16);
        s += __shfl_xor(s, 32);
        v[j] = 0.125f * s + b2[5 * (l & 7) + j];
    }
    float mx = v[0];
    #pragma unroll
    for (int j = 1; j < 5; ++j) mx = fmaxf(mx, v[j]);
    #pragma unroll
    for (int mask = 1; mask <= 4; mask <<= 1) mx = fmaxf(mx, __shfl_xor(mx, mask));
    float se = 0.f;
    #pragma unroll
    for (int j = 0; j < 5; ++j) se += __expf(v[j] - mx);
    #pragma unroll
    for (int mask = 1; mask <= 4; mask <<= 1) se += __shfl_xor(se, mask);
    float lse = mx + __logf(se);
    if (h == 0) {
        int o = node * 40 + 5 * (l & 7);
        #pragma unroll
        for (int j = 0; j < 5; ++j) out[o + j] = v[j] - lse;
    }
}

// ---------------- launch ----------------

extern "C" void kernel_launch(void* const* d_in, const int* in_sizes, int n_in,
                              void* d_out, int out_size, void* d_ws, size_t ws_size,
                              hipStream_t stream) {
    const float* x      = (const float*)d_in[0];
    const int*   ei     = (const int*)d_in[1];
    const float* W1     = (const float*)d_in[2];
    const float* a_src1 = (const float*)d_in[3];
    const float* a_dst1 = (const float*)d_in[4];
    const float* b1     = (const float*)d_in[5];
    const float* W2     = (const float*)d_in[6];
    const float* a_src2 = (const float*)d_in[7];
    const float* a_dst2 = (const float*)d_in[8];
    const float* b2     = (const float*)d_in[9];
    float* out = (float*)d_out;

    const int n    = in_sizes[0] / 128;   // 50000
    const int E    = in_sizes[1] / 2;     // 800000
    const int Etot = E + n;

    char* w = (char*)d_ws;
    auto take = [&](size_t bytes) {
        char* p = w;
        w += (bytes + 255) & ~(size_t)255;
        return p;
    };
    int*      deg    = (int*)take((size_t)n * 4);
    int*      rowptr = (int*)take((size_t)(n + 1) * 4);
    int*      cursor = (int*)take((size_t)n * 4);
    int*      ssrc   = (int*)take((size_t)Etot * 4);
    ushort_t* xb     = (ushort_t*)take((size_t)n * 128 * 2);
    ushort_t* w1b    = (ushort_t*)take((size_t)256 * 128 * 2);
    ushort_t* w2b    = (ushort_t*)take((size_t)320 * 256 * 2);
    ushort_t* h1b    = (ushort_t*)take((size_t)n * 256 * 2);
    ushort_t* helu   = (ushort_t*)take((size_t)n * 256 * 2);
    ushort_t* h2b    = (ushort_t*)take((size_t)n * 320 * 2);
    float*    als1   = (float*)take((size_t)n * 8 * 4);
    float*    ald1   = (float*)take((size_t)n * 8 * 4);
    float*    als2   = (float*)take((size_t)n * 8 * 4);
    float*    ald2   = (float*)take((size_t)n * 8 * 4);

    hipMemsetAsync(deg, 0, (size_t)n * 4, stream);

    // dtype converts
    conv_kernel<<<2048, 256, 0, stream>>>(x, xb, n * 128 / 4);
    conv_kernel<<<32, 256, 0, stream>>>(W1, w1b, 256 * 128 / 4);
    conv_kernel<<<80, 256, 0, stream>>>(W2, w2b, 320 * 256 / 4);

    // CSR
    int eb = (Etot + 255) / 256;
    count_kernel<<<eb, 256, 0, stream>>>(ei, E, n, deg);
    scan_kernel<<<1, 1024, 0, stream>>>(deg, rowptr, cursor, n);
    scatter_kernel<<<eb, 256, 0, stream>>>(ei, E, n, cursor, ssrc);

    int gb = (n + 63) / 64;
    int nb4 = (n + 3) / 4;

    // layer 1
    gemm_nt_bf16<16, 128><<<gb, 256, 0, stream>>>(xb, w1b, h1b, n);
    al_kernel<<<nb4, 256, 0, stream>>>(h1b, n, 256, a_src1, a_dst1, als1, ald1);
    agg1_kernel<<<nb4, 256, 0, stream>>>(h1b, als1, ald1, b1, rowptr, ssrc, helu, n);

    // layer 2
    gemm_nt_bf16<20, 256><<<gb, 256, 0, stream>>>(helu, w2b, h2b, n);
    al_kernel<<<nb4, 256, 0, stream>>>(h2b, n, 320, a_src2, a_dst2, als2, ald2);
    agg2_kernel<<<nb4, 256, 0, stream>>>(h2b, als2, ald2, b2, rowptr, ssrc, out, n);
}

// Round 4
// 536.249 us; speedup vs baseline: 1.3065x; 1.1760x over previous
//
#include <hip/hip_runtime.h>
#include <hip/hip_bf16.h>
#include <math.h>

typedef unsigned short ushort_t;
typedef __attribute__((ext_vector_type(8))) short short8;
typedef __attribute__((ext_vector_type(4))) float f32x4;
typedef __attribute__((ext_vector_type(4))) unsigned short u16x4;

static __device__ __forceinline__ float b2f(ushort_t u) {
    union { unsigned int i; float f; } v; v.i = ((unsigned int)u) << 16; return v.f;
}
static __device__ __forceinline__ ushort_t f2b(float f) {
    unsigned int x = __float_as_uint(f);
    unsigned int r = (x + 0x7fffu + ((x >> 16) & 1u)) >> 16;
    return (ushort_t)r;
}

// ---------------- fp32 -> bf16 convert ----------------

__global__ void conv_kernel(const float* __restrict__ src, ushort_t* __restrict__ dst, int n4) {
    for (int i = blockIdx.x * blockDim.x + threadIdx.x; i < n4; i += gridDim.x * blockDim.x) {
        float4 v = *(const float4*)(src + i * 4);
        u16x4 o = { f2b(v.x), f2b(v.y), f2b(v.z), f2b(v.w) };
        *(u16x4*)(dst + i * 4) = o;
    }
}

// ---------------- CSR build ----------------

__global__ void count_kernel(const int* __restrict__ ei, int E, int n, int* __restrict__ deg) {
    int e = blockIdx.x * blockDim.x + threadIdx.x;
    int Etot = E + n;
    if (e >= Etot) return;
    int dst = (e < E) ? ei[E + e] : (e - E);
    atomicAdd(&deg[dst], 1);
}

__global__ void scan_kernel(const int* __restrict__ deg, int* __restrict__ rowptr,
                            int* __restrict__ cursor, int n) {
    __shared__ int wsum[16];
    int t = threadIdx.x;
    int lane = t & 63, wid = t >> 6;
    int carry = 0;
    for (int base = 0; base < n; base += 1024) {
        int i = base + t;
        int v = (i < n) ? deg[i] : 0;
        int val = v;
        #pragma unroll
        for (int off = 1; off < 64; off <<= 1) {
            int nv = __shfl_up(val, off);
            if (lane >= off) val += nv;
        }
        if (lane == 63) wsum[wid] = val;
        __syncthreads();
        int wpre = 0, tot = 0;
        #pragma unroll
        for (int w = 0; w < 16; ++w) {
            int s = wsum[w];
            if (w < wid) wpre += s;
            tot += s;
        }
        int excl = carry + wpre + val - v;
        if (i < n) { rowptr[i] = excl; cursor[i] = excl; }
        carry += tot;
        __syncthreads();
    }
    if (t == 0) rowptr[n] = carry;
}

__global__ void scatter_kernel(const int* __restrict__ ei, int E, int n,
                               int* __restrict__ cursor, int* __restrict__ ssrc) {
    int e = blockIdx.x * blockDim.x + threadIdx.x;
    int Etot = E + n;
    if (e >= Etot) return;
    int src, dst;
    if (e < E) { src = ei[e]; dst = ei[E + e]; }
    else       { src = e - E; dst = e - E; }
    int pos = atomicAdd(&cursor[dst], 1);
    ssrc[pos] = src;
}

// ---------------- bf16 MFMA NT GEMM: C[M,N] = A[M,K] * B[N,K]^T ----------------

template<int NFRAG, int K>
__global__ __launch_bounds__(256) void gemm_nt_bf16(const ushort_t* __restrict__ A,
                                                    const ushort_t* __restrict__ B,
                                                    ushort_t* __restrict__ C, int M) {
    const int w = threadIdx.x >> 6, l = threadIdx.x & 63;
    const int r0 = blockIdx.x * 64 + w * 16;
    int arow = r0 + (l & 15);
    if (arow >= M) arow = M - 1;
    const int koff = (l >> 4) * 8;
    const int N = NFRAG * 16;
    f32x4 acc[NFRAG];
    #pragma unroll
    for (int i = 0; i < NFRAG; ++i) acc[i] = (f32x4){0.f, 0.f, 0.f, 0.f};
    const ushort_t* ap = A + (size_t)arow * K + koff;
    const ushort_t* bp = B + (size_t)(l & 15) * K + koff;
    #pragma unroll 1
    for (int k0 = 0; k0 < K; k0 += 32) {
        short8 a = *(const short8*)(ap + k0);
        #pragma unroll
        for (int nf = 0; nf < NFRAG; ++nf) {
            short8 b = *(const short8*)(bp + (size_t)nf * 16 * K + k0);
            acc[nf] = __builtin_amdgcn_mfma_f32_16x16x32_bf16(a, b, acc[nf], 0, 0, 0);
        }
    }
    const int crow0 = r0 + (l >> 4) * 4;
    #pragma unroll
    for (int nf = 0; nf < NFRAG; ++nf) {
        #pragma unroll
        for (int j = 0; j < 4; ++j) {
            int row = crow0 + j;
            if (row < M) C[(size_t)row * N + nf * 16 + (l & 15)] = f2b(acc[nf][j]);
        }
    }
}

// ---------------- attention logits from bf16 h ----------------

__global__ void al_kernel(const ushort_t* __restrict__ hmat, int n, int HC,
                          const float* __restrict__ a_src, const float* __restrict__ a_dst,
                          float* __restrict__ al_s, float* __restrict__ al_d) {
    int node = blockIdx.x * 4 + (threadIdx.x >> 6);
    if (node >= n) return;
    int l = threadIdx.x & 63;
    int q = HC >> 6;                       // elems per lane (4 or 5)
    const ushort_t* hp = hmat + (size_t)node * HC + q * l;
    float ps = 0.f, pd = 0.f;
    for (int j = 0; j < q; ++j) {
        float hv = b2f(hp[j]);
        ps += hv * a_src[q * l + j];
        pd += hv * a_dst[q * l + j];
    }
    #pragma unroll
    for (int mask = 1; mask <= 4; mask <<= 1) {
        ps += __shfl_xor(ps, mask);
        pd += __shfl_xor(pd, mask);
    }
    if ((l & 7) == 0) {
        al_s[node * 8 + (l >> 3)] = ps;
        al_d[node * 8 + (l >> 3)] = pd;
    }
}

// ---------------- layer-1 aggregation: online softmax, bf16 gather, +bias+ELU ----------------

__device__ __forceinline__ float lrelu(float e) { return (e > 0.f) ? e : 0.2f * e; }

__global__ void agg1_kernel(const ushort_t* __restrict__ h1, const float* __restrict__ als,
                            const float* __restrict__ aldv, const float* __restrict__ b1,
                            const int* __restrict__ rowptr, const int* __restrict__ ssrc,
                            ushort_t* __restrict__ hout, int n) {
    int node = blockIdx.x * 4 + (threadIdx.x >> 6);
    if (node >= n) return;
    int l = threadIdx.x & 63;
    int h = l >> 3;
    float ald = aldv[node * 8 + h];
    int beg = rowptr[node], end = rowptr[node + 1];
    float m = -1e30f, den = 0.f, a0 = 0.f, a1 = 0.f, a2 = 0.f, a3 = 0.f;
    for (int p = beg; p < end; ++p) {
        int s = ssrc[p];
        float e = lrelu(als[s * 8 + h] + ald);
        u16x4 hv = *(const u16x4*)(h1 + (size_t)s * 256 + l * 4);
        if (e > m + 8.f) {                      // defer-max rescale (rare)
            float f = __expf(m - e);
            den *= f; a0 *= f; a1 *= f; a2 *= f; a3 *= f;
            m = e;
        }
        float ee = __expf(e - m);
        den += ee;
        a0 += ee * b2f(hv.x); a1 += ee * b2f(hv.y);
        a2 += ee * b2f(hv.z); a3 += ee * b2f(hv.w);
    }
    float inv = 1.f / den;
    float4 bv = *(const float4*)(b1 + l * 4);
    float v0 = a0 * inv + bv.x, v1 = a1 * inv + bv.y;
    float v2 = a2 * inv + bv.z, v3 = a3 * inv + bv.w;
    u16x4 o;
    o.x = f2b((v0 > 0.f) ? v0 : __expf(v0) - 1.f);
    o.y = f2b((v1 > 0.f) ? v1 : __expf(v1) - 1.f);
    o.z = f2b((v2 > 0.f) ? v2 : __expf(v2) - 1.f);
    o.w = f2b((v3 > 0.f) ? v3 : __expf(v3) - 1.f);
    *(u16x4*)(hout + (size_t)node * 256 + l * 4) = o;
}

// ---------------- layer-2 aggregation: online softmax, aligned short8 gather,
//                  head-mean + bias + log_softmax ----------------
// lane l<40: head hd=l/5, class-group cg=l%5 (classes 8cg..8cg+8).
// feature load: h2[s*320 + hd*40 + cg*8], byte offset 80*hd+16*cg -> 16B aligned.

__global__ void agg2_kernel(const ushort_t* __restrict__ h2, const float* __restrict__ als,
                            const float* __restrict__ aldv, const float* __restrict__ b2,
                            const int* __restrict__ rowptr, const int* __restrict__ ssrc,
                            float* __restrict__ out, int n) {
    int node = blockIdx.x * 4 + (threadIdx.x >> 6);
    if (node >= n) return;
    int l = threadIdx.x & 63;
    int li = (l < 40) ? l : 0;              // idle lanes alias lane 0 (broadcast loads)
    int hd = li / 5;
    int cg = li - hd * 5;
    float ald = aldv[node * 8 + hd];
    int beg = rowptr[node], end = rowptr[node + 1];
    const ushort_t* base = h2 + hd * 40 + cg * 8;
    float m = -1e30f, den = 0.f;
    float a0 = 0.f, a1 = 0.f, a2 = 0.f, a3 = 0.f, a4 = 0.f, a5 = 0.f, a6 = 0.f, a7 = 0.f;
    for (int p = beg; p < end; ++p) {
        int s = ssrc[p];
        float e = lrelu(als[s * 8 + hd] + ald);
        short8 hv = *(const short8*)(base + (size_t)s * 320);
        if (e > m + 8.f) {
            float f = __expf(m - e);
            den *= f;
            a0 *= f; a1 *= f; a2 *= f; a3 *= f; a4 *= f; a5 *= f; a6 *= f; a7 *= f;
            m = e;
        }
        float ee = __expf(e - m);
        den += ee;
        a0 += ee * b2f((ushort_t)hv[0]); a1 += ee * b2f((ushort_t)hv[1]);
        a2 += ee * b2f((ushort_t)hv[2]); a3 += ee * b2f((ushort_t)hv[3]);
        a4 += ee * b2f((ushort_t)hv[4]); a5 += ee * b2f((ushort_t)hv[5]);
        a6 += ee * b2f((ushort_t)hv[6]); a7 += ee * b2f((ushort_t)hv[7]);
    }
    float inv = 1.f / den;
    float v[8] = {a0 * inv, a1 * inv, a2 * inv, a3 * inv,
                  a4 * inv, a5 * inv, a6 * inv, a7 * inv};
    // sum over heads: lanes hd*5+cg, strides 20/10/5 (lanes 0..4 end correct)
    #pragma unroll
    for (int j = 0; j < 8; ++j) {
        float s = v[j];
        s += __shfl_down(s, 20);
        s += __shfl_down(s, 10);
        s += __shfl_down(s, 5);
        v[j] = s;
    }
    if (l < 5) {
        float wv[8];
        #pragma unroll
        for (int j = 0; j < 8; ++j) wv[j] = 0.125f * v[j] + b2[l * 8 + j];
        float m8 = wv[0];
        #pragma unroll
        for (int j = 1; j < 8; ++j) m8 = fmaxf(m8, wv[j]);
        float mx = m8;
        #pragma unroll
        for (int k = 0; k < 5; ++k) mx = fmaxf(mx, __shfl(m8, k));
        float se8 = 0.f;
        #pragma unroll
        for (int j = 0; j < 8; ++j) se8 += __expf(wv[j] - mx);
        float se = 0.f;
        #pragma unroll
        for (int k = 0; k < 5; ++k) se += __shfl(se8, k);
        float lse = mx + __logf(se);
        float* op = out + (size_t)node * 40 + l * 8;
        float4 o0 = {wv[0] - lse, wv[1] - lse, wv[2] - lse, wv[3] - lse};
        float4 o1 = {wv[4] - lse, wv[5] - lse, wv[6] - lse, wv[7] - lse};
        *(float4*)op = o0;
        *(float4*)(op + 4) = o1;
    }
}

// ---------------- launch ----------------

extern "C" void kernel_launch(void* const* d_in, const int* in_sizes, int n_in,
                              void* d_out, int out_size, void* d_ws, size_t ws_size,
                              hipStream_t stream) {
    const float* x      = (const float*)d_in[0];
    const int*   ei     = (const int*)d_in[1];
    const float* W1     = (const float*)d_in[2];
    const float* a_src1 = (const float*)d_in[3];
    const float* a_dst1 = (const float*)d_in[4];
    const float* b1     = (const float*)d_in[5];
    const float* W2     = (const float*)d_in[6];
    const float* a_src2 = (const float*)d_in[7];
    const float* a_dst2 = (const float*)d_in[8];
    const float* b2     = (const float*)d_in[9];
    float* out = (float*)d_out;

    const int n    = in_sizes[0] / 128;   // 50000
    const int E    = in_sizes[1] / 2;     // 800000
    const int Etot = E + n;

    char* w = (char*)d_ws;
    auto take = [&](size_t bytes) {
        char* p = w;
        w += (bytes + 255) & ~(size_t)255;
        return p;
    };
    int*      deg    = (int*)take((size_t)n * 4);
    int*      rowptr = (int*)take((size_t)(n + 1) * 4);
    int*      cursor = (int*)take((size_t)n * 4);
    int*      ssrc   = (int*)take((size_t)Etot * 4);
    ushort_t* xb     = (ushort_t*)take((size_t)n * 128 * 2);
    ushort_t* w1b    = (ushort_t*)take((size_t)256 * 128 * 2);
    ushort_t* w2b    = (ushort_t*)take((size_t)320 * 256 * 2);
    ushort_t* h1b    = (ushort_t*)take((size_t)n * 256 * 2);
    ushort_t* helu   = (ushort_t*)take((size_t)n * 256 * 2);
    ushort_t* h2b    = (ushort_t*)take((size_t)n * 320 * 2);
    float*    als1   = (float*)take((size_t)n * 8 * 4);
    float*    ald1   = (float*)take((size_t)n * 8 * 4);
    float*    als2   = (float*)take((size_t)n * 8 * 4);
    float*    ald2   = (float*)take((size_t)n * 8 * 4);

    hipMemsetAsync(deg, 0, (size_t)n * 4, stream);

    // dtype converts
    conv_kernel<<<2048, 256, 0, stream>>>(x, xb, n * 128 / 4);
    conv_kernel<<<32, 256, 0, stream>>>(W1, w1b, 256 * 128 / 4);
    conv_kernel<<<80, 256, 0, stream>>>(W2, w2b, 320 * 256 / 4);

    // CSR
    int eb = (Etot + 255) / 256;
    count_kernel<<<eb, 256, 0, stream>>>(ei, E, n, deg);
    scan_kernel<<<1, 1024, 0, stream>>>(deg, rowptr, cursor, n);
    scatter_kernel<<<eb, 256, 0, stream>>>(ei, E, n, cursor, ssrc);

    int gb = (n + 63) / 64;
    int nb4 = (n + 3) / 4;

    // layer 1
    gemm_nt_bf16<16, 128><<<gb, 256, 0, stream>>>(xb, w1b, h1b, n);
    al_kernel<<<nb4, 256, 0, stream>>>(h1b, n, 256, a_src1, a_dst1, als1, ald1);
    agg1_kernel<<<nb4, 256, 0, stream>>>(h1b, als1, ald1, b1, rowptr, ssrc, helu, n);

    // layer 2
    gemm_nt_bf16<20, 256><<<gb, 256, 0, stream>>>(helu, w2b, h2b, n);
    al_kernel<<<nb4, 256, 0, stream>>>(h2b, n, 320, a_src2, a_dst2, als2, ald2);
    agg2_kernel<<<nb4, 256, 0, stream>>>(h2b, als2, ald2, b2, rowptr, ssrc, out, n);
}

// Round 6
// 441.501 us; speedup vs baseline: 1.5869x; 1.2146x over previous
//
#include <hip/hip_runtime.h>
#include <hip/hip_bf16.h>
#include <math.h>

typedef unsigned short ushort_t;
typedef __attribute__((ext_vector_type(8))) short short8;
typedef __attribute__((ext_vector_type(4))) float f32x4;
typedef __attribute__((ext_vector_type(4))) unsigned short u16x4;

static __device__ __forceinline__ float b2f(ushort_t u) {
    union { unsigned int i; float f; } v; v.i = ((unsigned int)u) << 16; return v.f;
}
static __device__ __forceinline__ ushort_t f2b(float f) {
    unsigned int x = __float_as_uint(f);
    unsigned int r = (x + 0x7fffu + ((x >> 16) & 1u)) >> 16;
    return (ushort_t)r;
}

// ---------------- fp32 -> bf16 convert ----------------

__global__ void conv_kernel(const float* __restrict__ src, ushort_t* __restrict__ dst, int n4) {
    for (int i = blockIdx.x * blockDim.x + threadIdx.x; i < n4; i += gridDim.x * blockDim.x) {
        float4 v = *(const float4*)(src + i * 4);
        u16x4 o = { f2b(v.x), f2b(v.y), f2b(v.z), f2b(v.w) };
        *(u16x4*)(dst + i * 4) = o;
    }
}

// pad rows: als1/als2 row n = -1e30 (sentinel -> zero weight), h1b/h2b row n = 0
__global__ void pad_row_kernel(float* als1, float* als2, ushort_t* h1b, ushort_t* h2b, int n) {
    int t = threadIdx.x;
    if (t < 8) { als1[(size_t)n * 8 + t] = -1e30f; als2[(size_t)n * 8 + t] = -1e30f; }
    if (t < 256) h1b[(size_t)n * 256 + t] = 0;
    if (t < 320) h2b[(size_t)n * 320 + t] = 0;
}

// ---------------- CSR build (rows padded to multiples of 4) ----------------

__global__ void count_kernel(const int* __restrict__ ei, int E, int n, int* __restrict__ deg) {
    int e = blockIdx.x * blockDim.x + threadIdx.x;
    int Etot = E + n;
    if (e >= Etot) return;
    int dst = (e < E) ? ei[E + e] : (e - E);
    atomicAdd(&deg[dst], 1);
}

__global__ void scan_kernel(const int* __restrict__ deg, int* __restrict__ rowptr,
                            int* __restrict__ cursor, int n) {
    __shared__ int wsum[16];
    int t = threadIdx.x;
    int lane = t & 63, wid = t >> 6;
    int carry = 0;
    for (int base = 0; base < n; base += 1024) {
        int i = base + t;
        int v = (i < n) ? ((deg[i] + 3) & ~3) : 0;   // padded degree
        int val = v;
        #pragma unroll
        for (int off = 1; off < 64; off <<= 1) {
            int nv = __shfl_up(val, off);
            if (lane >= off) val += nv;
        }
        if (lane == 63) wsum[wid] = val;
        __syncthreads();
        int wpre = 0, tot = 0;
        #pragma unroll
        for (int w = 0; w < 16; ++w) {
            int s = wsum[w];
            if (w < wid) wpre += s;
            tot += s;
        }
        int excl = carry + wpre + val - v;
        if (i < n) { rowptr[i] = excl; cursor[i] = excl; }
        carry += tot;
        __syncthreads();
    }
    if (t == 0) rowptr[n] = carry;
}

__global__ void scatter_kernel(const int* __restrict__ ei, int E, int n,
                               int* __restrict__ cursor, int* __restrict__ ssrc) {
    int e = blockIdx.x * blockDim.x + threadIdx.x;
    int Etot = E + n;
    if (e >= Etot) return;
    int src, dst;
    if (e < E) { src = ei[e]; dst = ei[E + e]; }
    else       { src = e - E; dst = e - E; }
    int pos = atomicAdd(&cursor[dst], 1);
    ssrc[pos] = src;
}

__global__ void pad_fill_kernel(const int* __restrict__ rowptr, const int* __restrict__ cursor,
                                int* __restrict__ ssrc, int n) {
    int i = blockIdx.x * blockDim.x + threadIdx.x;
    if (i >= n) return;
    int p = cursor[i], e = rowptr[i + 1];
    for (; p < e; ++p) ssrc[p] = n;   // sentinel
}

// ---------------- bf16 MFMA NT GEMM: C[M,N] = A[M,K] * B[N,K]^T ----------------

template<int NFRAG, int K>
__global__ __launch_bounds__(256) void gemm_nt_bf16(const ushort_t* __restrict__ A,
                                                    const ushort_t* __restrict__ B,
                                                    ushort_t* __restrict__ C, int M) {
    const int w = threadIdx.x >> 6, l = threadIdx.x & 63;
    const int r0 = blockIdx.x * 64 + w * 16;
    int arow = r0 + (l & 15);
    if (arow >= M) arow = M - 1;
    const int koff = (l >> 4) * 8;
    const int N = NFRAG * 16;
    f32x4 acc[NFRAG];
    #pragma unroll
    for (int i = 0; i < NFRAG; ++i) acc[i] = (f32x4){0.f, 0.f, 0.f, 0.f};
    const ushort_t* ap = A + (size_t)arow * K + koff;
    const ushort_t* bp = B + (size_t)(l & 15) * K + koff;
    #pragma unroll 1
    for (int k0 = 0; k0 < K; k0 += 32) {
        short8 a = *(const short8*)(ap + k0);
        #pragma unroll
        for (int nf = 0; nf < NFRAG; ++nf) {
            short8 b = *(const short8*)(bp + (size_t)nf * 16 * K + k0);
            acc[nf] = __builtin_amdgcn_mfma_f32_16x16x32_bf16(a, b, acc[nf], 0, 0, 0);
        }
    }
    const int crow0 = r0 + (l >> 4) * 4;
    #pragma unroll
    for (int nf = 0; nf < NFRAG; ++nf) {
        #pragma unroll
        for (int j = 0; j < 4; ++j) {
            int row = crow0 + j;
            if (row < M) C[(size_t)row * N + nf * 16 + (l & 15)] = f2b(acc[nf][j]);
        }
    }
}

// ---------------- attention logits ----------------

__global__ void al1_kernel(const ushort_t* __restrict__ h, int n,
                           const float* __restrict__ a_src, const float* __restrict__ a_dst,
                           float* __restrict__ al_s, float* __restrict__ al_d) {
    int node = blockIdx.x * 4 + (threadIdx.x >> 6);
    if (node >= n) return;
    int l = threadIdx.x & 63;
    u16x4 hv = *(const u16x4*)(h + (size_t)node * 256 + l * 4);
    float4 as = *(const float4*)(a_src + l * 4);
    float4 ad = *(const float4*)(a_dst + l * 4);
    float h0 = b2f(hv.x), h1 = b2f(hv.y), h2 = b2f(hv.z), h3 = b2f(hv.w);
    float ps = h0 * as.x + h1 * as.y + h2 * as.z + h3 * as.w;
    float pd = h0 * ad.x + h1 * ad.y + h2 * ad.z + h3 * ad.w;
    #pragma unroll
    for (int mask = 1; mask <= 4; mask <<= 1) {
        ps += __shfl_xor(ps, mask);
        pd += __shfl_xor(pd, mask);
    }
    if ((l & 7) == 0) {
        al_s[node * 8 + (l >> 3)] = ps;
        al_d[node * 8 + (l >> 3)] = pd;
    }
}

// layer-2: 40 lanes, head hd=l/5, class-group cg=l%5 -> aligned short8
__global__ void al2_kernel(const ushort_t* __restrict__ h, int n,
                           const float* __restrict__ a_src, const float* __restrict__ a_dst,
                           float* __restrict__ al_s, float* __restrict__ al_d) {
    int node = blockIdx.x * 4 + (threadIdx.x >> 6);
    if (node >= n) return;
    int l = threadIdx.x & 63;
    int li = (l < 40) ? l : 39;
    int hd = li / 5, cg = li - hd * 5;
    int off = hd * 40 + cg * 8;
    short8 hv = *(const short8*)(h + (size_t)node * 320 + off);
    float ps = 0.f, pd = 0.f;
    #pragma unroll
    for (int j = 0; j < 8; ++j) {
        float f = b2f((ushort_t)hv[j]);
        ps += f * a_src[off + j];
        pd += f * a_dst[off + j];
    }
    ps += __shfl_down(ps, 1); pd += __shfl_down(pd, 1);
    ps += __shfl_down(ps, 2); pd += __shfl_down(pd, 2);
    float ps4 = __shfl_down(ps, 4), pd4 = __shfl_down(pd, 4);
    ps += ps4; pd += pd4;
    if (l < 40 && cg == 0) {
        al_s[node * 8 + hd] = ps;
        al_d[node * 8 + hd] = pd;
    }
}

// ---------------- layer-1 aggregation: 4-edge unrolled online softmax ----------------

__device__ __forceinline__ float lrelu(float e) { return (e > 0.f) ? e : 0.2f * e; }

__global__ void agg1_kernel(const ushort_t* __restrict__ h1, const float* __restrict__ als,
                            const float* __restrict__ aldv, const float* __restrict__ b1,
                            const int* __restrict__ rowptr, const int* __restrict__ ssrc,
                            ushort_t* __restrict__ hout, int n) {
    int node = blockIdx.x * 4 + (threadIdx.x >> 6);
    if (node >= n) return;
    int l = threadIdx.x & 63;
    int h = l >> 3;
    float ald = aldv[node * 8 + h];
    int beg = rowptr[node], end = rowptr[node + 1];
    float m = -1e30f, den = 0.f, a0 = 0.f, a1 = 0.f, a2 = 0.f, a3 = 0.f;
    for (int p = beg; p < end; p += 4) {
        int4 s4 = *(const int4*)(ssrc + p);
        float e0 = lrelu(als[s4.x * 8 + h] + ald);
        float e1 = lrelu(als[s4.y * 8 + h] + ald);
        float e2 = lrelu(als[s4.z * 8 + h] + ald);
        float e3 = lrelu(als[s4.w * 8 + h] + ald);
        u16x4 f0 = *(const u16x4*)(h1 + (size_t)s4.x * 256 + l * 4);
        u16x4 f1 = *(const u16x4*)(h1 + (size_t)s4.y * 256 + l * 4);
        u16x4 f2 = *(const u16x4*)(h1 + (size_t)s4.z * 256 + l * 4);
        u16x4 f3 = *(const u16x4*)(h1 + (size_t)s4.w * 256 + l * 4);
        float em = fmaxf(fmaxf(e0, e1), fmaxf(e2, e3));
        if (em > m + 8.f) {
            float f = __expf(m - em);
            den *= f; a0 *= f; a1 *= f; a2 *= f; a3 *= f;
            m = em;
        }
        float w0 = __expf(e0 - m), w1 = __expf(e1 - m);
        float w2 = __expf(e2 - m), w3 = __expf(e3 - m);
        den += (w0 + w1) + (w2 + w3);
        a0 += w0 * b2f(f0.x) + w1 * b2f(f1.x) + w2 * b2f(f2.x) + w3 * b2f(f3.x);
        a1 += w0 * b2f(f0.y) + w1 * b2f(f1.y) + w2 * b2f(f2.y) + w3 * b2f(f3.y);
        a2 += w0 * b2f(f0.z) + w1 * b2f(f1.z) + w2 * b2f(f2.z) + w3 * b2f(f3.z);
        a3 += w0 * b2f(f0.w) + w1 * b2f(f1.w) + w2 * b2f(f2.w) + w3 * b2f(f3.w);
    }
    float inv = 1.f / den;
    float4 bv = *(const float4*)(b1 + l * 4);
    float v0 = a0 * inv + bv.x, v1 = a1 * inv + bv.y;
    float v2 = a2 * inv + bv.z, v3 = a3 * inv + bv.w;
    u16x4 o;
    o.x = f2b((v0 > 0.f) ? v0 : __expf(v0) - 1.f);
    o.y = f2b((v1 > 0.f) ? v1 : __expf(v1) - 1.f);
    o.z = f2b((v2 > 0.f) ? v2 : __expf(v2) - 1.f);
    o.w = f2b((v3 > 0.f) ? v3 : __expf(v3) - 1.f);
    *(u16x4*)(hout + (size_t)node * 256 + l * 4) = o;
}

// ---------------- layer-2 aggregation: 4-edge unrolled + head-mean + log_softmax ----------------

__global__ void agg2_kernel(const ushort_t* __restrict__ h2, const float* __restrict__ als,
                            const float* __restrict__ aldv, const float* __restrict__ b2,
                            const int* __restrict__ rowptr, const int* __restrict__ ssrc,
                            float* __restrict__ out, int n) {
    int node = blockIdx.x * 4 + (threadIdx.x >> 6);
    if (node >= n) return;
    int l = threadIdx.x & 63;
    int li = (l < 40) ? l : 0;
    int hd = li / 5;
    int cg = li - hd * 5;
    float ald = aldv[node * 8 + hd];
    int beg = rowptr[node], end = rowptr[node + 1];
    const ushort_t* base = h2 + hd * 40 + cg * 8;
    float m = -1e30f, den = 0.f;
    float a0 = 0.f, a1 = 0.f, a2 = 0.f, a3 = 0.f, a4 = 0.f, a5 = 0.f, a6 = 0.f, a7 = 0.f;
    for (int p = beg; p < end; p += 4) {
        int4 s4 = *(const int4*)(ssrc + p);
        float e0 = lrelu(als[s4.x * 8 + hd] + ald);
        float e1 = lrelu(als[s4.y * 8 + hd] + ald);
        float e2 = lrelu(als[s4.z * 8 + hd] + ald);
        float e3 = lrelu(als[s4.w * 8 + hd] + ald);
        short8 f0 = *(const short8*)(base + (size_t)s4.x * 320);
        short8 f1 = *(const short8*)(base + (size_t)s4.y * 320);
        short8 f2 = *(const short8*)(base + (size_t)s4.z * 320);
        short8 f3 = *(const short8*)(base + (size_t)s4.w * 320);
        float em = fmaxf(fmaxf(e0, e1), fmaxf(e2, e3));
        if (em > m + 8.f) {
            float f = __expf(m - em);
            den *= f;
            a0 *= f; a1 *= f; a2 *= f; a3 *= f; a4 *= f; a5 *= f; a6 *= f; a7 *= f;
            m = em;
        }
        float w0 = __expf(e0 - m), w1 = __expf(e1 - m);
        float w2 = __expf(e2 - m), w3 = __expf(e3 - m);
        den += (w0 + w1) + (w2 + w3);
        a0 += w0 * b2f((ushort_t)f0[0]) + w1 * b2f((ushort_t)f1[0]) + w2 * b2f((ushort_t)f2[0]) + w3 * b2f((ushort_t)f3[0]);
        a1 += w0 * b2f((ushort_t)f0[1]) + w1 * b2f((ushort_t)f1[1]) + w2 * b2f((ushort_t)f2[1]) + w3 * b2f((ushort_t)f3[1]);
        a2 += w0 * b2f((ushort_t)f0[2]) + w1 * b2f((ushort_t)f1[2]) + w2 * b2f((ushort_t)f2[2]) + w3 * b2f((ushort_t)f3[2]);
        a3 += w0 * b2f((ushort_t)f0[3]) + w1 * b2f((ushort_t)f1[3]) + w2 * b2f((ushort_t)f2[3]) + w3 * b2f((ushort_t)f3[3]);
        a4 += w0 * b2f((ushort_t)f0[4]) + w1 * b2f((ushort_t)f1[4]) + w2 * b2f((ushort_t)f2[4]) + w3 * b2f((ushort_t)f3[4]);
        a5 += w0 * b2f((ushort_t)f0[5]) + w1 * b2f((ushort_t)f1[5]) + w2 * b2f((ushort_t)f2[5]) + w3 * b2f((ushort_t)f3[5]);
        a6 += w0 * b2f((ushort_t)f0[6]) + w1 * b2f((ushort_t)f1[6]) + w2 * b2f((ushort_t)f2[6]) + w3 * b2f((ushort_t)f3[6]);
        a7 += w0 * b2f((ushort_t)f0[7]) + w1 * b2f((ushort_t)f1[7]) + w2 * b2f((ushort_t)f2[7]) + w3 * b2f((ushort_t)f3[7]);
    }
    float inv = 1.f / den;
    float v[8] = {a0 * inv, a1 * inv, a2 * inv, a3 * inv,
                  a4 * inv, a5 * inv, a6 * inv, a7 * inv};
    #pragma unroll
    for (int j = 0; j < 8; ++j) {
        float s = v[j];
        s += __shfl_down(s, 20);
        s += __shfl_down(s, 10);
        s += __shfl_down(s, 5);
        v[j] = s;
    }
    if (l < 5) {
        float wv[8];
        #pragma unroll
        for (int j = 0; j < 8; ++j) wv[j] = 0.125f * v[j] + b2[l * 8 + j];
        float m8 = wv[0];
        #pragma unroll
        for (int j = 1; j < 8; ++j) m8 = fmaxf(m8, wv[j]);
        float mx = m8;
        #pragma unroll
        for (int k = 0; k < 5; ++k) mx = fmaxf(mx, __shfl(m8, k));
        float se8 = 0.f;
        #pragma unroll
        for (int j = 0; j < 8; ++j) se8 += __expf(wv[j] - mx);
        float se = 0.f;
        #pragma unroll
        for (int k = 0; k < 5; ++k) se += __shfl(se8, k);
        float lse = mx + __logf(se);
        float* op = out + (size_t)node * 40 + l * 8;
        float4 o0 = {wv[0] - lse, wv[1] - lse, wv[2] - lse, wv[3] - lse};
        float4 o1 = {wv[4] - lse, wv[5] - lse, wv[6] - lse, wv[7] - lse};
        *(float4*)op = o0;
        *(float4*)(op + 4) = o1;
    }
}

// ---------------- launch ----------------

extern "C" void kernel_launch(void* const* d_in, const int* in_sizes, int n_in,
                              void* d_out, int out_size, void* d_ws, size_t ws_size,
                              hipStream_t stream) {
    const float* x      = (const float*)d_in[0];
    const int*   ei     = (const int*)d_in[1];
    const float* W1     = (const float*)d_in[2];
    const float* a_src1 = (const float*)d_in[3];
    const float* a_dst1 = (const float*)d_in[4];
    const float* b1     = (const float*)d_in[5];
    const float* W2     = (const float*)d_in[6];
    const float* a_src2 = (const float*)d_in[7];
    const float* a_dst2 = (const float*)d_in[8];
    const float* b2     = (const float*)d_in[9];
    float* out = (float*)d_out;

    const int n    = in_sizes[0] / 128;   // 50000
    const int E    = in_sizes[1] / 2;     // 800000
    const int Etot = E + n;

    char* w = (char*)d_ws;
    auto take = [&](size_t bytes) {
        char* p = w;
        w += (bytes + 255) & ~(size_t)255;
        return p;
    };
    int*      deg    = (int*)take((size_t)n * 4);
    int*      rowptr = (int*)take((size_t)(n + 1) * 4);
    int*      cursor = (int*)take((size_t)n * 4);
    int*      ssrc   = (int*)take(((size_t)Etot + 3 * (size_t)n + 16) * 4);  // padded CSR
    ushort_t* xb     = (ushort_t*)take((size_t)n * 128 * 2);
    ushort_t* w1b    = (ushort_t*)take((size_t)256 * 128 * 2);
    ushort_t* w2b    = (ushort_t*)take((size_t)320 * 256 * 2);
    ushort_t* h1b    = (ushort_t*)take((size_t)(n + 1) * 256 * 2);
    ushort_t* helu   = (ushort_t*)take((size_t)n * 256 * 2);
    ushort_t* h2b    = (ushort_t*)take((size_t)(n + 1) * 320 * 2);
    float*    als1   = (float*)take((size_t)(n + 1) * 8 * 4);
    float*    ald1   = (float*)take((size_t)n * 8 * 4);
    float*    als2   = (float*)take((size_t)(n + 1) * 8 * 4);
    float*    ald2   = (float*)take((size_t)n * 8 * 4);

    hipMemsetAsync(deg, 0, (size_t)n * 4, stream);
    pad_row_kernel<<<1, 512, 0, stream>>>(als1, als2, h1b, h2b, n);

    // dtype converts
    conv_kernel<<<2048, 256, 0, stream>>>(x, xb, n * 128 / 4);
    conv_kernel<<<32, 256, 0, stream>>>(W1, w1b, 256 * 128 / 4);
    conv_kernel<<<80, 256, 0, stream>>>(W2, w2b, 320 * 256 / 4);

    // CSR (4-padded rows)
    int eb = (Etot + 255) / 256;
    count_kernel<<<eb, 256, 0, stream>>>(ei, E, n, deg);
    scan_kernel<<<1, 1024, 0, stream>>>(deg, rowptr, cursor, n);
    scatter_kernel<<<eb, 256, 0, stream>>>(ei, E, n, cursor, ssrc);
    pad_fill_kernel<<<(n + 255) / 256, 256, 0, stream>>>(rowptr, cursor, ssrc, n);

    int gb = (n + 63) / 64;
    int nb4 = (n + 3) / 4;

    // layer 1
    gemm_nt_bf16<16, 128><<<gb, 256, 0, stream>>>(xb, w1b, h1b, n);
    al1_kernel<<<nb4, 256, 0, stream>>>(h1b, n, a_src1, a_dst1, als1, ald1);
    agg1_kernel<<<nb4, 256, 0, stream>>>(h1b, als1, ald1, b1, rowptr, ssrc, helu, n);

    // layer 2
    gemm_nt_bf16<20, 256><<<gb, 256, 0, stream>>>(helu, w2b, h2b, n);
    al2_kernel<<<nb4, 256, 0, stream>>>(h2b, n, a_src2, a_dst2, als2, ald2);
    agg2_kernel<<<nb4, 256, 0, stream>>>(h2b, als2, ald2, b2, rowptr, ssrc, out, n);
}

// Round 8
// 364.221 us; speedup vs baseline: 1.9236x; 1.2122x over previous
//
#include <hip/hip_runtime.h>
#include <hip/hip_bf16.h>
#include <math.h>

typedef unsigned short ushort_t;
typedef __attribute__((ext_vector_type(8))) short short8;
typedef __attribute__((ext_vector_type(4))) float f32x4;
typedef __attribute__((ext_vector_type(4))) unsigned short u16x4;

static __device__ __forceinline__ float b2f(ushort_t u) {
    union { unsigned int i; float f; } v; v.i = ((unsigned int)u) << 16; return v.f;
}
static __device__ __forceinline__ ushort_t f2b(float f) {
    unsigned int x = __float_as_uint(f);
    unsigned int r = (x + 0x7fffu + ((x >> 16) & 1u)) >> 16;
    return (ushort_t)r;
}

// ---------------- fp32 -> bf16 convert ----------------

__global__ void conv_kernel(const float* __restrict__ src, ushort_t* __restrict__ dst, int n4) {
    for (int i = blockIdx.x * blockDim.x + threadIdx.x; i < n4; i += gridDim.x * blockDim.x) {
        float4 v = *(const float4*)(src + i * 4);
        u16x4 o = { f2b(v.x), f2b(v.y), f2b(v.z), f2b(v.w) };
        *(u16x4*)(dst + i * 4) = o;
    }
}

// pad rows: als1/als2 row n = -1e30 (sentinel -> zero weight), h1b/h2b row n = 0
__global__ void pad_row_kernel(float* als1, float* als2, ushort_t* h1b, ushort_t* h2b, int n) {
    int t = threadIdx.x;
    if (t < 8) { als1[(size_t)n * 8 + t] = -1e30f; als2[(size_t)n * 8 + t] = -1e30f; }
    if (t < 256) h1b[(size_t)n * 256 + t] = 0;
    if (t < 320) h2b[(size_t)n * 320 + t] = 0;
}

// ---------------- CSR build (rows padded to multiples of 4) ----------------

__global__ void count_kernel(const int* __restrict__ ei, int E, int n, int* __restrict__ deg) {
    int e = blockIdx.x * blockDim.x + threadIdx.x;
    int Etot = E + n;
    if (e >= Etot) return;
    int dst = (e < E) ? ei[E + e] : (e - E);
    atomicAdd(&deg[dst], 1);
}

__global__ void scan_kernel(const int* __restrict__ deg, int* __restrict__ rowptr,
                            int* __restrict__ cursor, int n) {
    __shared__ int wsum[16];
    int t = threadIdx.x;
    int lane = t & 63, wid = t >> 6;
    int carry = 0;
    for (int base = 0; base < n; base += 1024) {
        int i = base + t;
        int v = (i < n) ? ((deg[i] + 3) & ~3) : 0;   // padded degree
        int val = v;
        #pragma unroll
        for (int off = 1; off < 64; off <<= 1) {
            int nv = __shfl_up(val, off);
            if (lane >= off) val += nv;
        }
        if (lane == 63) wsum[wid] = val;
        __syncthreads();
        int wpre = 0, tot = 0;
        #pragma unroll
        for (int w = 0; w < 16; ++w) {
            int s = wsum[w];
            if (w < wid) wpre += s;
            tot += s;
        }
        int excl = carry + wpre + val - v;
        if (i < n) { rowptr[i] = excl; cursor[i] = excl; }
        carry += tot;
        __syncthreads();
    }
    if (t == 0) rowptr[n] = carry;
}

__global__ void scatter_kernel(const int* __restrict__ ei, int E, int n,
                               int* __restrict__ cursor, int* __restrict__ ssrc) {
    int e = blockIdx.x * blockDim.x + threadIdx.x;
    int Etot = E + n;
    if (e >= Etot) return;
    int src, dst;
    if (e < E) { src = ei[e]; dst = ei[E + e]; }
    else       { src = e - E; dst = e - E; }
    int pos = atomicAdd(&cursor[dst], 1);
    ssrc[pos] = src;
}

__global__ void pad_fill_kernel(const int* __restrict__ rowptr, const int* __restrict__ cursor,
                                int* __restrict__ ssrc, int n) {
    int i = blockIdx.x * blockDim.x + threadIdx.x;
    if (i >= n) return;
    int p = cursor[i], e = rowptr[i + 1];
    for (; p < e; ++p) ssrc[p] = n;   // sentinel
}

// ---------------- bf16 MFMA NT GEMM, LDS-staged B: C[M,N] = A[M,K] * B[N,K]^T ----------------
// block = 512 threads = 8 waves, BM = 128 rows. B k-slice (N x 32) double-buffered in LDS.
// LDS row stride 40 elems (80B): 16B-aligned ds_read_b128, bank-starts (20r)%32 -> 2-way only.

template<int NFRAG, int K>
__global__ __launch_bounds__(512) void gemm_lds_bf16(const ushort_t* __restrict__ A,
                                                     const ushort_t* __restrict__ B,
                                                     ushort_t* __restrict__ C, int M) {
    constexpr int N = NFRAG * 16;
    constexpr int RS = 40;                 // LDS row stride in elems
    constexpr int NK = K / 32;
    __shared__ ushort_t Bs[2][N * RS];
    const int t = threadIdx.x;
    const int w = t >> 6, l = t & 63;
    const int r0 = blockIdx.x * 128 + w * 16;
    int arow = r0 + (l & 15);
    if (arow >= M) arow = M - 1;
    const int koff = (l >> 4) * 8;
    const ushort_t* ap = A + (size_t)arow * K + koff;

    f32x4 acc[NFRAG];
    #pragma unroll
    for (int i = 0; i < NFRAG; ++i) acc[i] = (f32x4){0.f, 0.f, 0.f, 0.f};

    auto stage = [&](int buf, int k0) {
        #pragma unroll
        for (int c = t; c < N * 4; c += 512) {
            int row = c >> 2, part = (c & 3) << 3;           // part in elems
            *(short8*)&Bs[buf][row * RS + part] =
                *(const short8*)(B + (size_t)row * K + k0 + part);
        }
    };

    stage(0, 0);
    __syncthreads();
    #pragma unroll
    for (int kk = 0; kk < NK; ++kk) {
        int buf = kk & 1;
        if (kk + 1 < NK) stage(buf ^ 1, (kk + 1) * 32);
        short8 a = *(const short8*)(ap + kk * 32);
        #pragma unroll
        for (int nf = 0; nf < NFRAG; ++nf) {
            short8 b = *(const short8*)&Bs[buf][(nf * 16 + (l & 15)) * RS + koff];
            acc[nf] = __builtin_amdgcn_mfma_f32_16x16x32_bf16(a, b, acc[nf], 0, 0, 0);
        }
        __syncthreads();
    }

    const int crow0 = r0 + (l >> 4) * 4;
    #pragma unroll
    for (int nf = 0; nf < NFRAG; ++nf) {
        #pragma unroll
        for (int j = 0; j < 4; ++j) {
            int row = crow0 + j;
            if (row < M) C[(size_t)row * N + nf * 16 + (l & 15)] = f2b(acc[nf][j]);
        }
    }
}

// ---------------- attention logits ----------------

__global__ void al1_kernel(const ushort_t* __restrict__ h, int n,
                           const float* __restrict__ a_src, const float* __restrict__ a_dst,
                           float* __restrict__ al_s, float* __restrict__ al_d) {
    int node = blockIdx.x * 4 + (threadIdx.x >> 6);
    if (node >= n) return;
    int l = threadIdx.x & 63;
    u16x4 hv = *(const u16x4*)(h + (size_t)node * 256 + l * 4);
    float4 as = *(const float4*)(a_src + l * 4);
    float4 ad = *(const float4*)(a_dst + l * 4);
    float h0 = b2f(hv.x), h1 = b2f(hv.y), h2 = b2f(hv.z), h3 = b2f(hv.w);
    float ps = h0 * as.x + h1 * as.y + h2 * as.z + h3 * as.w;
    float pd = h0 * ad.x + h1 * ad.y + h2 * ad.z + h3 * ad.w;
    #pragma unroll
    for (int mask = 1; mask <= 4; mask <<= 1) {
        ps += __shfl_xor(ps, mask);
        pd += __shfl_xor(pd, mask);
    }
    if ((l & 7) == 0) {
        al_s[node * 8 + (l >> 3)] = ps;
        al_d[node * 8 + (l >> 3)] = pd;
    }
}

// layer-2: 40 lanes, head hd=l/5, class-group cg=l%5 -> aligned short8
__global__ void al2_kernel(const ushort_t* __restrict__ h, int n,
                           const float* __restrict__ a_src, const float* __restrict__ a_dst,
                           float* __restrict__ al_s, float* __restrict__ al_d) {
    int node = blockIdx.x * 4 + (threadIdx.x >> 6);
    if (node >= n) return;
    int l = threadIdx.x & 63;
    int li = (l < 40) ? l : 39;
    int hd = li / 5, cg = li - hd * 5;
    int off = hd * 40 + cg * 8;
    short8 hv = *(const short8*)(h + (size_t)node * 320 + off);
    float ps = 0.f, pd = 0.f;
    #pragma unroll
    for (int j = 0; j < 8; ++j) {
        float f = b2f((ushort_t)hv[j]);
        ps += f * a_src[off + j];
        pd += f * a_dst[off + j];
    }
    ps += __shfl_down(ps, 1); pd += __shfl_down(pd, 1);
    ps += __shfl_down(ps, 2); pd += __shfl_down(pd, 2);
    float ps4 = __shfl_down(ps, 4), pd4 = __shfl_down(pd, 4);
    ps += ps4; pd += pd4;
    if (l < 40 && cg == 0) {
        al_s[node * 8 + hd] = ps;
        al_d[node * 8 + hd] = pd;
    }
}

// ---------------- layer-1 aggregation: 4-edge unrolled online softmax ----------------

__device__ __forceinline__ float lrelu(float e) { return (e > 0.f) ? e : 0.2f * e; }

__global__ void agg1_kernel(const ushort_t* __restrict__ h1, const float* __restrict__ als,
                            const float* __restrict__ aldv, const float* __restrict__ b1,
                            const int* __restrict__ rowptr, const int* __restrict__ ssrc,
                            ushort_t* __restrict__ hout, int n) {
    int node = blockIdx.x * 4 + (threadIdx.x >> 6);
    if (node >= n) return;
    int l = threadIdx.x & 63;
    int h = l >> 3;
    float ald = aldv[node * 8 + h];
    int beg = rowptr[node], end = rowptr[node + 1];
    float m = -1e30f, den = 0.f, a0 = 0.f, a1 = 0.f, a2 = 0.f, a3 = 0.f;
    for (int p = beg; p < end; p += 4) {
        int4 s4 = *(const int4*)(ssrc + p);
        float e0 = lrelu(als[s4.x * 8 + h] + ald);
        float e1 = lrelu(als[s4.y * 8 + h] + ald);
        float e2 = lrelu(als[s4.z * 8 + h] + ald);
        float e3 = lrelu(als[s4.w * 8 + h] + ald);
        u16x4 f0 = *(const u16x4*)(h1 + (size_t)s4.x * 256 + l * 4);
        u16x4 f1 = *(const u16x4*)(h1 + (size_t)s4.y * 256 + l * 4);
        u16x4 f2 = *(const u16x4*)(h1 + (size_t)s4.z * 256 + l * 4);
        u16x4 f3 = *(const u16x4*)(h1 + (size_t)s4.w * 256 + l * 4);
        float em = fmaxf(fmaxf(e0, e1), fmaxf(e2, e3));
        if (em > m + 8.f) {
            float f = __expf(m - em);
            den *= f; a0 *= f; a1 *= f; a2 *= f; a3 *= f;
            m = em;
        }
        float w0 = __expf(e0 - m), w1 = __expf(e1 - m);
        float w2 = __expf(e2 - m), w3 = __expf(e3 - m);
        den += (w0 + w1) + (w2 + w3);
        a0 += w0 * b2f(f0.x) + w1 * b2f(f1.x) + w2 * b2f(f2.x) + w3 * b2f(f3.x);
        a1 += w0 * b2f(f0.y) + w1 * b2f(f1.y) + w2 * b2f(f2.y) + w3 * b2f(f3.y);
        a2 += w0 * b2f(f0.z) + w1 * b2f(f1.z) + w2 * b2f(f2.z) + w3 * b2f(f3.z);
        a3 += w0 * b2f(f0.w) + w1 * b2f(f1.w) + w2 * b2f(f2.w) + w3 * b2f(f3.w);
    }
    float inv = 1.f / den;
    float4 bv = *(const float4*)(b1 + l * 4);
    float v0 = a0 * inv + bv.x, v1 = a1 * inv + bv.y;
    float v2 = a2 * inv + bv.z, v3 = a3 * inv + bv.w;
    u16x4 o;
    o.x = f2b((v0 > 0.f) ? v0 : __expf(v0) - 1.f);
    o.y = f2b((v1 > 0.f) ? v1 : __expf(v1) - 1.f);
    o.z = f2b((v2 > 0.f) ? v2 : __expf(v2) - 1.f);
    o.w = f2b((v3 > 0.f) ? v3 : __expf(v3) - 1.f);
    *(u16x4*)(hout + (size_t)node * 256 + l * 4) = o;
}

// ---------------- layer-2 aggregation: 4-edge unrolled + head-mean + log_softmax ----------------

__global__ void agg2_kernel(const ushort_t* __restrict__ h2, const float* __restrict__ als,
                            const float* __restrict__ aldv, const float* __restrict__ b2,
                            const int* __restrict__ rowptr, const int* __restrict__ ssrc,
                            float* __restrict__ out, int n) {
    int node = blockIdx.x * 4 + (threadIdx.x >> 6);
    if (node >= n) return;
    int l = threadIdx.x & 63;
    int li = (l < 40) ? l : 0;
    int hd = li / 5;
    int cg = li - hd * 5;
    float ald = aldv[node * 8 + hd];
    int beg = rowptr[node], end = rowptr[node + 1];
    const ushort_t* base = h2 + hd * 40 + cg * 8;
    float m = -1e30f, den = 0.f;
    float a0 = 0.f, a1 = 0.f, a2 = 0.f, a3 = 0.f, a4 = 0.f, a5 = 0.f, a6 = 0.f, a7 = 0.f;
    for (int p = beg; p < end; p += 4) {
        int4 s4 = *(const int4*)(ssrc + p);
        float e0 = lrelu(als[s4.x * 8 + hd] + ald);
        float e1 = lrelu(als[s4.y * 8 + hd] + ald);
        float e2 = lrelu(als[s4.z * 8 + hd] + ald);
        float e3 = lrelu(als[s4.w * 8 + hd] + ald);
        short8 f0 = *(const short8*)(base + (size_t)s4.x * 320);
        short8 f1 = *(const short8*)(base + (size_t)s4.y * 320);
        short8 f2 = *(const short8*)(base + (size_t)s4.z * 320);
        short8 f3 = *(const short8*)(base + (size_t)s4.w * 320);
        float em = fmaxf(fmaxf(e0, e1), fmaxf(e2, e3));
        if (em > m + 8.f) {
            float f = __expf(m - em);
            den *= f;
            a0 *= f; a1 *= f; a2 *= f; a3 *= f; a4 *= f; a5 *= f; a6 *= f; a7 *= f;
            m = em;
        }
        float w0 = __expf(e0 - m), w1 = __expf(e1 - m);
        float w2 = __expf(e2 - m), w3 = __expf(e3 - m);
        den += (w0 + w1) + (w2 + w3);
        a0 += w0 * b2f((ushort_t)f0[0]) + w1 * b2f((ushort_t)f1[0]) + w2 * b2f((ushort_t)f2[0]) + w3 * b2f((ushort_t)f3[0]);
        a1 += w0 * b2f((ushort_t)f0[1]) + w1 * b2f((ushort_t)f1[1]) + w2 * b2f((ushort_t)f2[1]) + w3 * b2f((ushort_t)f3[1]);
        a2 += w0 * b2f((ushort_t)f0[2]) + w1 * b2f((ushort_t)f1[2]) + w2 * b2f((ushort_t)f2[2]) + w3 * b2f((ushort_t)f3[2]);
        a3 += w0 * b2f((ushort_t)f0[3]) + w1 * b2f((ushort_t)f1[3]) + w2 * b2f((ushort_t)f2[3]) + w3 * b2f((ushort_t)f3[3]);
        a4 += w0 * b2f((ushort_t)f0[4]) + w1 * b2f((ushort_t)f1[4]) + w2 * b2f((ushort_t)f2[4]) + w3 * b2f((ushort_t)f3[4]);
        a5 += w0 * b2f((ushort_t)f0[5]) + w1 * b2f((ushort_t)f1[5]) + w2 * b2f((ushort_t)f2[5]) + w3 * b2f((ushort_t)f3[5]);
        a6 += w0 * b2f((ushort_t)f0[6]) + w1 * b2f((ushort_t)f1[6]) + w2 * b2f((ushort_t)f2[6]) + w3 * b2f((ushort_t)f3[6]);
        a7 += w0 * b2f((ushort_t)f0[7]) + w1 * b2f((ushort_t)f1[7]) + w2 * b2f((ushort_t)f2[7]) + w3 * b2f((ushort_t)f3[7]);
    }
    float inv = 1.f / den;
    float v[8] = {a0 * inv, a1 * inv, a2 * inv, a3 * inv,
                  a4 * inv, a5 * inv, a6 * inv, a7 * inv};
    #pragma unroll
    for (int j = 0; j < 8; ++j) {
        float s = v[j];
        s += __shfl_down(s, 20);
        s += __shfl_down(s, 10);
        s += __shfl_down(s, 5);
        v[j] = s;
    }
    if (l < 5) {
        float wv[8];
        #pragma unroll
        for (int j = 0; j < 8; ++j) wv[j] = 0.125f * v[j] + b2[l * 8 + j];
        float m8 = wv[0];
        #pragma unroll
        for (int j = 1; j < 8; ++j) m8 = fmaxf(m8, wv[j]);
        float mx = m8;
        #pragma unroll
        for (int k = 0; k < 5; ++k) mx = fmaxf(mx, __shfl(m8, k));
        float se8 = 0.f;
        #pragma unroll
        for (int j = 0; j < 8; ++j) se8 += __expf(wv[j] - mx);
        float se = 0.f;
        #pragma unroll
        for (int k = 0; k < 5; ++k) se += __shfl(se8, k);
        float lse = mx + __logf(se);
        float* op = out + (size_t)node * 40 + l * 8;
        float4 o0 = {wv[0] - lse, wv[1] - lse, wv[2] - lse, wv[3] - lse};
        float4 o1 = {wv[4] - lse, wv[5] - lse, wv[6] - lse, wv[7] - lse};
        *(float4*)op = o0;
        *(float4*)(op + 4) = o1;
    }
}

// ---------------- launch ----------------

extern "C" void kernel_launch(void* const* d_in, const int* in_sizes, int n_in,
                              void* d_out, int out_size, void* d_ws, size_t ws_size,
                              hipStream_t stream) {
    const float* x      = (const float*)d_in[0];
    const int*   ei     = (const int*)d_in[1];
    const float* W1     = (const float*)d_in[2];
    const float* a_src1 = (const float*)d_in[3];
    const float* a_dst1 = (const float*)d_in[4];
    const float* b1     = (const float*)d_in[5];
    const float* W2     = (const float*)d_in[6];
    const float* a_src2 = (const float*)d_in[7];
    const float* a_dst2 = (const float*)d_in[8];
    const float* b2     = (const float*)d_in[9];
    float* out = (float*)d_out;

    const int n    = in_sizes[0] / 128;   // 50000
    const int E    = in_sizes[1] / 2;     // 800000
    const int Etot = E + n;

    char* w = (char*)d_ws;
    auto take = [&](size_t bytes) {
        char* p = w;
        w += (bytes + 255) & ~(size_t)255;
        return p;
    };
    int*      deg    = (int*)take((size_t)n * 4);
    int*      rowptr = (int*)take((size_t)(n + 1) * 4);
    int*      cursor = (int*)take((size_t)n * 4);
    int*      ssrc   = (int*)take(((size_t)Etot + 3 * (size_t)n + 16) * 4);  // padded CSR
    ushort_t* xb     = (ushort_t*)take((size_t)n * 128 * 2);
    ushort_t* w1b    = (ushort_t*)take((size_t)256 * 128 * 2);
    ushort_t* w2b    = (ushort_t*)take((size_t)320 * 256 * 2);
    ushort_t* h1b    = (ushort_t*)take((size_t)(n + 1) * 256 * 2);
    ushort_t* helu   = (ushort_t*)take((size_t)n * 256 * 2);
    ushort_t* h2b    = (ushort_t*)take((size_t)(n + 1) * 320 * 2);
    float*    als1   = (float*)take((size_t)(n + 1) * 8 * 4);
    float*    ald1   = (float*)take((size_t)n * 8 * 4);
    float*    als2   = (float*)take((size_t)(n + 1) * 8 * 4);
    float*    ald2   = (float*)take((size_t)n * 8 * 4);

    hipMemsetAsync(deg, 0, (size_t)n * 4, stream);
    pad_row_kernel<<<1, 512, 0, stream>>>(als1, als2, h1b, h2b, n);

    // dtype converts
    conv_kernel<<<2048, 256, 0, stream>>>(x, xb, n * 128 / 4);
    conv_kernel<<<32, 256, 0, stream>>>(W1, w1b, 256 * 128 / 4);
    conv_kernel<<<80, 256, 0, stream>>>(W2, w2b, 320 * 256 / 4);

    // CSR (4-padded rows)
    int eb = (Etot + 255) / 256;
    count_kernel<<<eb, 256, 0, stream>>>(ei, E, n, deg);
    scan_kernel<<<1, 1024, 0, stream>>>(deg, rowptr, cursor, n);
    scatter_kernel<<<eb, 256, 0, stream>>>(ei, E, n, cursor, ssrc);
    pad_fill_kernel<<<(n + 255) / 256, 256, 0, stream>>>(rowptr, cursor, ssrc, n);

    int gb = (n + 127) / 128;
    int nb4 = (n + 3) / 4;

    // layer 1
    gemm_lds_bf16<16, 128><<<gb, 512, 0, stream>>>(xb, w1b, h1b, n);
    al1_kernel<<<nb4, 256, 0, stream>>>(h1b, n, a_src1, a_dst1, als1, ald1);
    agg1_kernel<<<nb4, 256, 0, stream>>>(h1b, als1, ald1, b1, rowptr, ssrc, helu, n);

    // layer 2
    gemm_lds_bf16<20, 256><<<gb, 512, 0, stream>>>(helu, w2b, h2b, n);
    al2_kernel<<<nb4, 256, 0, stream>>>(h2b, n, a_src2, a_dst2, als2, ald2);
    agg2_kernel<<<nb4, 256, 0, stream>>>(h2b, als2, ald2, b2, rowptr, ssrc, out, n);
}

// Round 9
// 358.009 us; speedup vs baseline: 1.9569x; 1.0174x over previous
//
#include <hip/hip_runtime.h>
#include <hip/hip_bf16.h>
#include <math.h>

typedef unsigned short ushort_t;
typedef __attribute__((ext_vector_type(8))) short short8;
typedef __attribute__((ext_vector_type(4))) float f32x4;
typedef __attribute__((ext_vector_type(4))) unsigned short u16x4;

static __device__ __forceinline__ float b2f(ushort_t u) {
    union { unsigned int i; float f; } v; v.i = ((unsigned int)u) << 16; return v.f;
}
static __device__ __forceinline__ ushort_t f2b(float f) {
    unsigned int x = __float_as_uint(f);
    unsigned int r = (x + 0x7fffu + ((x >> 16) & 1u)) >> 16;
    return (ushort_t)r;
}

// ---------------- fp32 -> bf16 convert ----------------

__global__ void conv_kernel(const float* __restrict__ src, ushort_t* __restrict__ dst, int n4) {
    for (int i = blockIdx.x * blockDim.x + threadIdx.x; i < n4; i += gridDim.x * blockDim.x) {
        float4 v = *(const float4*)(src + i * 4);
        u16x4 o = { f2b(v.x), f2b(v.y), f2b(v.z), f2b(v.w) };
        *(u16x4*)(dst + i * 4) = o;
    }
}

// folded attention rows: wa[col][k] = sum_c W[(h*Cd+c)*K + k] * a[h*Cd+c]; col<8 -> a_src (h=col), col>=8 -> a_dst
template<int K, int Cd>
__global__ void build_wa(const float* __restrict__ W, const float* __restrict__ as,
                         const float* __restrict__ ad, ushort_t* __restrict__ Bext, int rowoff) {
    int tid = blockIdx.x * blockDim.x + threadIdx.x;
    if (tid >= 16 * K) return;
    int col = tid / K, k = tid - col * K;
    const float* a = (col < 8) ? as : ad;
    int h = col & 7;
    float s = 0.f;
    #pragma unroll 4
    for (int c = 0; c < Cd; ++c)
        s += W[(size_t)(h * Cd + c) * K + k] * a[h * Cd + c];
    Bext[(size_t)(rowoff + col) * K + k] = f2b(s);
}

// pad rows: als1/als2 row n = -1e30 (sentinel -> zero weight), h1b/h2b row n = 0
__global__ void pad_row_kernel(float* als1, float* als2, ushort_t* h1b, ushort_t* h2b, int n) {
    int t = threadIdx.x;
    if (t < 8) { als1[(size_t)n * 8 + t] = -1e30f; als2[(size_t)n * 8 + t] = -1e30f; }
    if (t < 256) h1b[(size_t)n * 256 + t] = 0;
    if (t < 320) h2b[(size_t)n * 320 + t] = 0;
}

// ---------------- CSR build (rows padded to multiples of 8) ----------------

__global__ void count_kernel(const int* __restrict__ ei, int E, int n, int* __restrict__ deg) {
    int e = blockIdx.x * blockDim.x + threadIdx.x;
    int Etot = E + n;
    if (e >= Etot) return;
    int dst = (e < E) ? ei[E + e] : (e - E);
    atomicAdd(&deg[dst], 1);
}

__global__ void scan_kernel(const int* __restrict__ deg, int* __restrict__ rowptr,
                            int* __restrict__ cursor, int n) {
    __shared__ int wsum[16];
    int t = threadIdx.x;
    int lane = t & 63, wid = t >> 6;
    int carry = 0;
    for (int base = 0; base < n; base += 1024) {
        int i = base + t;
        int v = (i < n) ? ((deg[i] + 7) & ~7) : 0;   // padded degree
        int val = v;
        #pragma unroll
        for (int off = 1; off < 64; off <<= 1) {
            int nv = __shfl_up(val, off);
            if (lane >= off) val += nv;
        }
        if (lane == 63) wsum[wid] = val;
        __syncthreads();
        int wpre = 0, tot = 0;
        #pragma unroll
        for (int w = 0; w < 16; ++w) {
            int s = wsum[w];
            if (w < wid) wpre += s;
            tot += s;
        }
        int excl = carry + wpre + val - v;
        if (i < n) { rowptr[i] = excl; cursor[i] = excl; }
        carry += tot;
        __syncthreads();
    }
    if (t == 0) rowptr[n] = carry;
}

__global__ void scatter_kernel(const int* __restrict__ ei, int E, int n,
                               int* __restrict__ cursor, int* __restrict__ ssrc) {
    int e = blockIdx.x * blockDim.x + threadIdx.x;
    int Etot = E + n;
    if (e >= Etot) return;
    int src, dst;
    if (e < E) { src = ei[e]; dst = ei[E + e]; }
    else       { src = e - E; dst = e - E; }
    int pos = atomicAdd(&cursor[dst], 1);
    ssrc[pos] = src;
}

__global__ void pad_fill_kernel(const int* __restrict__ rowptr, const int* __restrict__ cursor,
                                int* __restrict__ ssrc, int n) {
    int i = blockIdx.x * blockDim.x + threadIdx.x;
    if (i >= n) return;
    int p = cursor[i], e = rowptr[i + 1];
    for (; p < e; ++p) ssrc[p] = n;   // sentinel
}

// ---------------- bf16 MFMA NT GEMM + fused attention logits ----------------
// B has NFRAG*16 rows: first (NFRAG-1)*16 = W rows -> C; last 16 = wa rows -> als/ald.
// block = 512 threads = 8 waves, BM = 128 rows; B k-slice double-buffered in LDS.

template<int NFRAG, int K>
__global__ __launch_bounds__(512) void gemm_lds_al(const ushort_t* __restrict__ A,
                                                   const ushort_t* __restrict__ B,
                                                   ushort_t* __restrict__ C,
                                                   float* __restrict__ als,
                                                   float* __restrict__ ald, int M) {
    constexpr int N = NFRAG * 16;
    constexpr int NOUT = (NFRAG - 1) * 16;
    constexpr int RS = 40;                 // LDS row stride in elems
    constexpr int NK = K / 32;
    __shared__ ushort_t Bs[2][N * RS];
    const int t = threadIdx.x;
    const int w = t >> 6, l = t & 63;
    const int r0 = blockIdx.x * 128 + w * 16;
    int arow = r0 + (l & 15);
    if (arow >= M) arow = M - 1;
    const int koff = (l >> 4) * 8;
    const ushort_t* ap = A + (size_t)arow * K + koff;

    f32x4 acc[NFRAG];
    #pragma unroll
    for (int i = 0; i < NFRAG; ++i) acc[i] = (f32x4){0.f, 0.f, 0.f, 0.f};

    auto stage = [&](int buf, int k0) {
        #pragma unroll
        for (int c = t; c < N * 4; c += 512) {
            int row = c >> 2, part = (c & 3) << 3;           // part in elems
            *(short8*)&Bs[buf][row * RS + part] =
                *(const short8*)(B + (size_t)row * K + k0 + part);
        }
    };

    stage(0, 0);
    __syncthreads();
    #pragma unroll
    for (int kk = 0; kk < NK; ++kk) {
        int buf = kk & 1;
        if (kk + 1 < NK) stage(buf ^ 1, (kk + 1) * 32);
        short8 a = *(const short8*)(ap + kk * 32);
        #pragma unroll
        for (int nf = 0; nf < NFRAG; ++nf) {
            short8 b = *(const short8*)&Bs[buf][(nf * 16 + (l & 15)) * RS + koff];
            acc[nf] = __builtin_amdgcn_mfma_f32_16x16x32_bf16(a, b, acc[nf], 0, 0, 0);
        }
        __syncthreads();
    }

    const int crow0 = r0 + (l >> 4) * 4;
    #pragma unroll
    for (int nf = 0; nf < NFRAG - 1; ++nf) {
        #pragma unroll
        for (int j = 0; j < 4; ++j) {
            int row = crow0 + j;
            if (row < M) C[(size_t)row * NOUT + nf * 16 + (l & 15)] = f2b(acc[nf][j]);
        }
    }
    {   // attention-logit fragment
        int col = l & 15;
        float* dstp = (col < 8) ? als : ald;
        int h = col & 7;
        #pragma unroll
        for (int j = 0; j < 4; ++j) {
            int row = crow0 + j;
            if (row < M) dstp[(size_t)row * 8 + h] = acc[NFRAG - 1][j];
        }
    }
}

// ---------------- layer-1 aggregation: 8-edge unrolled online softmax ----------------

__device__ __forceinline__ float lrelu(float e) { return (e > 0.f) ? e : 0.2f * e; }

__global__ void agg1_kernel(const ushort_t* __restrict__ h1, const float* __restrict__ als,
                            const float* __restrict__ aldv, const float* __restrict__ b1,
                            const int* __restrict__ rowptr, const int* __restrict__ ssrc,
                            ushort_t* __restrict__ hout, int n) {
    int node = blockIdx.x * 4 + (threadIdx.x >> 6);
    if (node >= n) return;
    int l = threadIdx.x & 63;
    int h = l >> 3;
    float ald = aldv[node * 8 + h];
    int beg = rowptr[node], end = rowptr[node + 1];
    float m = -1e30f, den = 0.f, a0 = 0.f, a1 = 0.f, a2 = 0.f, a3 = 0.f;
    for (int p = beg; p < end; p += 8) {
        int4 sA = *(const int4*)(ssrc + p);
        int4 sB = *(const int4*)(ssrc + p + 4);
        float e0 = lrelu(als[sA.x * 8 + h] + ald);
        float e1 = lrelu(als[sA.y * 8 + h] + ald);
        float e2 = lrelu(als[sA.z * 8 + h] + ald);
        float e3 = lrelu(als[sA.w * 8 + h] + ald);
        float e4 = lrelu(als[sB.x * 8 + h] + ald);
        float e5 = lrelu(als[sB.y * 8 + h] + ald);
        float e6 = lrelu(als[sB.z * 8 + h] + ald);
        float e7 = lrelu(als[sB.w * 8 + h] + ald);
        u16x4 f0 = *(const u16x4*)(h1 + (size_t)sA.x * 256 + l * 4);
        u16x4 f1 = *(const u16x4*)(h1 + (size_t)sA.y * 256 + l * 4);
        u16x4 f2 = *(const u16x4*)(h1 + (size_t)sA.z * 256 + l * 4);
        u16x4 f3 = *(const u16x4*)(h1 + (size_t)sA.w * 256 + l * 4);
        u16x4 f4 = *(const u16x4*)(h1 + (size_t)sB.x * 256 + l * 4);
        u16x4 f5 = *(const u16x4*)(h1 + (size_t)sB.y * 256 + l * 4);
        u16x4 f6 = *(const u16x4*)(h1 + (size_t)sB.z * 256 + l * 4);
        u16x4 f7 = *(const u16x4*)(h1 + (size_t)sB.w * 256 + l * 4);
        float em = fmaxf(fmaxf(fmaxf(e0, e1), fmaxf(e2, e3)),
                         fmaxf(fmaxf(e4, e5), fmaxf(e6, e7)));
        if (em > m + 8.f) {
            float f = __expf(m - em);
            den *= f; a0 *= f; a1 *= f; a2 *= f; a3 *= f;
            m = em;
        }
        float w0 = __expf(e0 - m), w1 = __expf(e1 - m);
        float w2 = __expf(e2 - m), w3 = __expf(e3 - m);
        float w4 = __expf(e4 - m), w5 = __expf(e5 - m);
        float w6 = __expf(e6 - m), w7 = __expf(e7 - m);
        den += ((w0 + w1) + (w2 + w3)) + ((w4 + w5) + (w6 + w7));
        a0 += w0 * b2f(f0.x) + w1 * b2f(f1.x) + w2 * b2f(f2.x) + w3 * b2f(f3.x)
            + w4 * b2f(f4.x) + w5 * b2f(f5.x) + w6 * b2f(f6.x) + w7 * b2f(f7.x);
        a1 += w0 * b2f(f0.y) + w1 * b2f(f1.y) + w2 * b2f(f2.y) + w3 * b2f(f3.y)
            + w4 * b2f(f4.y) + w5 * b2f(f5.y) + w6 * b2f(f6.y) + w7 * b2f(f7.y);
        a2 += w0 * b2f(f0.z) + w1 * b2f(f1.z) + w2 * b2f(f2.z) + w3 * b2f(f3.z)
            + w4 * b2f(f4.z) + w5 * b2f(f5.z) + w6 * b2f(f6.z) + w7 * b2f(f7.z);
        a3 += w0 * b2f(f0.w) + w1 * b2f(f1.w) + w2 * b2f(f2.w) + w3 * b2f(f3.w)
            + w4 * b2f(f4.w) + w5 * b2f(f5.w) + w6 * b2f(f6.w) + w7 * b2f(f7.w);
    }
    float inv = 1.f / den;
    float4 bv = *(const float4*)(b1 + l * 4);
    float v0 = a0 * inv + bv.x, v1 = a1 * inv + bv.y;
    float v2 = a2 * inv + bv.z, v3 = a3 * inv + bv.w;
    u16x4 o;
    o.x = f2b((v0 > 0.f) ? v0 : __expf(v0) - 1.f);
    o.y = f2b((v1 > 0.f) ? v1 : __expf(v1) - 1.f);
    o.z = f2b((v2 > 0.f) ? v2 : __expf(v2) - 1.f);
    o.w = f2b((v3 > 0.f) ? v3 : __expf(v3) - 1.f);
    *(u16x4*)(hout + (size_t)node * 256 + l * 4) = o;
}

// ---------------- layer-2 aggregation: 8-edge unrolled + head-mean + log_softmax ----------------

__global__ void agg2_kernel(const ushort_t* __restrict__ h2, const float* __restrict__ als,
                            const float* __restrict__ aldv, const float* __restrict__ b2,
                            const int* __restrict__ rowptr, const int* __restrict__ ssrc,
                            float* __restrict__ out, int n) {
    int node = blockIdx.x * 4 + (threadIdx.x >> 6);
    if (node >= n) return;
    int l = threadIdx.x & 63;
    int li = (l < 40) ? l : 0;
    int hd = li / 5;
    int cg = li - hd * 5;
    float ald = aldv[node * 8 + hd];
    int beg = rowptr[node], end = rowptr[node + 1];
    const ushort_t* base = h2 + hd * 40 + cg * 8;
    float m = -1e30f, den = 0.f;
    float a0 = 0.f, a1 = 0.f, a2 = 0.f, a3 = 0.f, a4 = 0.f, a5 = 0.f, a6 = 0.f, a7 = 0.f;
    for (int p = beg; p < end; p += 8) {
        int4 sA = *(const int4*)(ssrc + p);
        int4 sB = *(const int4*)(ssrc + p + 4);
        float e0 = lrelu(als[sA.x * 8 + hd] + ald);
        float e1 = lrelu(als[sA.y * 8 + hd] + ald);
        float e2 = lrelu(als[sA.z * 8 + hd] + ald);
        float e3 = lrelu(als[sA.w * 8 + hd] + ald);
        float e4 = lrelu(als[sB.x * 8 + hd] + ald);
        float e5 = lrelu(als[sB.y * 8 + hd] + ald);
        float e6 = lrelu(als[sB.z * 8 + hd] + ald);
        float e7 = lrelu(als[sB.w * 8 + hd] + ald);
        short8 f0 = *(const short8*)(base + (size_t)sA.x * 320);
        short8 f1 = *(const short8*)(base + (size_t)sA.y * 320);
        short8 f2 = *(const short8*)(base + (size_t)sA.z * 320);
        short8 f3 = *(const short8*)(base + (size_t)sA.w * 320);
        short8 f4 = *(const short8*)(base + (size_t)sB.x * 320);
        short8 f5 = *(const short8*)(base + (size_t)sB.y * 320);
        short8 f6 = *(const short8*)(base + (size_t)sB.z * 320);
        short8 f7 = *(const short8*)(base + (size_t)sB.w * 320);
        float em = fmaxf(fmaxf(fmaxf(e0, e1), fmaxf(e2, e3)),
                         fmaxf(fmaxf(e4, e5), fmaxf(e6, e7)));
        if (em > m + 8.f) {
            float f = __expf(m - em);
            den *= f;
            a0 *= f; a1 *= f; a2 *= f; a3 *= f; a4 *= f; a5 *= f; a6 *= f; a7 *= f;
            m = em;
        }
        float w0 = __expf(e0 - m), w1 = __expf(e1 - m);
        float w2 = __expf(e2 - m), w3 = __expf(e3 - m);
        float w4 = __expf(e4 - m), w5 = __expf(e5 - m);
        float w6 = __expf(e6 - m), w7 = __expf(e7 - m);
        den += ((w0 + w1) + (w2 + w3)) + ((w4 + w5) + (w6 + w7));
        #define ACC(idx, reg) \
            reg += w0 * b2f((ushort_t)f0[idx]) + w1 * b2f((ushort_t)f1[idx]) \
                 + w2 * b2f((ushort_t)f2[idx]) + w3 * b2f((ushort_t)f3[idx]) \
                 + w4 * b2f((ushort_t)f4[idx]) + w5 * b2f((ushort_t)f5[idx]) \
                 + w6 * b2f((ushort_t)f6[idx]) + w7 * b2f((ushort_t)f7[idx]);
        ACC(0, a0) ACC(1, a1) ACC(2, a2) ACC(3, a3)
        ACC(4, a4) ACC(5, a5) ACC(6, a6) ACC(7, a7)
        #undef ACC
    }
    float inv = 1.f / den;
    float v[8] = {a0 * inv, a1 * inv, a2 * inv, a3 * inv,
                  a4 * inv, a5 * inv, a6 * inv, a7 * inv};
    #pragma unroll
    for (int j = 0; j < 8; ++j) {
        float s = v[j];
        s += __shfl_down(s, 20);
        s += __shfl_down(s, 10);
        s += __shfl_down(s, 5);
        v[j] = s;
    }
    if (l < 5) {
        float wv[8];
        #pragma unroll
        for (int j = 0; j < 8; ++j) wv[j] = 0.125f * v[j] + b2[l * 8 + j];
        float m8 = wv[0];
        #pragma unroll
        for (int j = 1; j < 8; ++j) m8 = fmaxf(m8, wv[j]);
        float mx = m8;
        #pragma unroll
        for (int k = 0; k < 5; ++k) mx = fmaxf(mx, __shfl(m8, k));
        float se8 = 0.f;
        #pragma unroll
        for (int j = 0; j < 8; ++j) se8 += __expf(wv[j] - mx);
        float se = 0.f;
        #pragma unroll
        for (int k = 0; k < 5; ++k) se += __shfl(se8, k);
        float lse = mx + __logf(se);
        float* op = out + (size_t)node * 40 + l * 8;
        float4 o0 = {wv[0] - lse, wv[1] - lse, wv[2] - lse, wv[3] - lse};
        float4 o1 = {wv[4] - lse, wv[5] - lse, wv[6] - lse, wv[7] - lse};
        *(float4*)op = o0;
        *(float4*)(op + 4) = o1;
    }
}

// ---------------- launch ----------------

extern "C" void kernel_launch(void* const* d_in, const int* in_sizes, int n_in,
                              void* d_out, int out_size, void* d_ws, size_t ws_size,
                              hipStream_t stream) {
    const float* x      = (const float*)d_in[0];
    const int*   ei     = (const int*)d_in[1];
    const float* W1     = (const float*)d_in[2];
    const float* a_src1 = (const float*)d_in[3];
    const float* a_dst1 = (const float*)d_in[4];
    const float* b1     = (const float*)d_in[5];
    const float* W2     = (const float*)d_in[6];
    const float* a_src2 = (const float*)d_in[7];
    const float* a_dst2 = (const float*)d_in[8];
    const float* b2     = (const float*)d_in[9];
    float* out = (float*)d_out;

    const int n    = in_sizes[0] / 128;   // 50000
    const int E    = in_sizes[1] / 2;     // 800000
    const int Etot = E + n;

    char* w = (char*)d_ws;
    auto take = [&](size_t bytes) {
        char* p = w;
        w += (bytes + 255) & ~(size_t)255;
        return p;
    };
    int*      deg    = (int*)take((size_t)n * 4);
    int*      rowptr = (int*)take((size_t)(n + 1) * 4);
    int*      cursor = (int*)take((size_t)n * 4);
    int*      ssrc   = (int*)take(((size_t)Etot + 7 * (size_t)n + 16) * 4);  // 8-padded CSR
    ushort_t* xb     = (ushort_t*)take((size_t)n * 128 * 2);
    ushort_t* w1b    = (ushort_t*)take((size_t)272 * 128 * 2);   // 256 W1 rows + 16 wa rows
    ushort_t* w2b    = (ushort_t*)take((size_t)336 * 256 * 2);   // 320 W2 rows + 16 wa rows
    ushort_t* h1b    = (ushort_t*)take((size_t)(n + 1) * 256 * 2);
    ushort_t* helu   = (ushort_t*)take((size_t)n * 256 * 2);
    ushort_t* h2b    = (ushort_t*)take((size_t)(n + 1) * 320 * 2);
    float*    als1   = (float*)take((size_t)(n + 1) * 8 * 4);
    float*    ald1   = (float*)take((size_t)n * 8 * 4);
    float*    als2   = (float*)take((size_t)(n + 1) * 8 * 4);
    float*    ald2   = (float*)take((size_t)n * 8 * 4);

    hipMemsetAsync(deg, 0, (size_t)n * 4, stream);
    pad_row_kernel<<<1, 512, 0, stream>>>(als1, als2, h1b, h2b, n);

    // dtype converts + folded attention rows
    conv_kernel<<<2048, 256, 0, stream>>>(x, xb, n * 128 / 4);
    conv_kernel<<<32, 256, 0, stream>>>(W1, w1b, 256 * 128 / 4);
    conv_kernel<<<80, 256, 0, stream>>>(W2, w2b, 320 * 256 / 4);
    build_wa<128, 32><<<8, 256, 0, stream>>>(W1, a_src1, a_dst1, w1b, 256);
    build_wa<256, 40><<<16, 256, 0, stream>>>(W2, a_src2, a_dst2, w2b, 320);

    // CSR (8-padded rows)
    int eb = (Etot + 255) / 256;
    count_kernel<<<eb, 256, 0, stream>>>(ei, E, n, deg);
    scan_kernel<<<1, 1024, 0, stream>>>(deg, rowptr, cursor, n);
    scatter_kernel<<<eb, 256, 0, stream>>>(ei, E, n, cursor, ssrc);
    pad_fill_kernel<<<(n + 255) / 256, 256, 0, stream>>>(rowptr, cursor, ssrc, n);

    int gb = (n + 127) / 128;
    int nb4 = (n + 3) / 4;

    // layer 1 (gemm computes h1 AND als1/ald1)
    gemm_lds_al<17, 128><<<gb, 512, 0, stream>>>(xb, w1b, h1b, als1, ald1, n);
    agg1_kernel<<<nb4, 256, 0, stream>>>(h1b, als1, ald1, b1, rowptr, ssrc, helu, n);

    // layer 2
    gemm_lds_al<21, 256><<<gb, 512, 0, stream>>>(helu, w2b, h2b, als2, ald2, n);
    agg2_kernel<<<nb4, 256, 0, stream>>>(h2b, als2, ald2, b2, rowptr, ssrc, out, n);
}